// Round 2
// baseline (1971.325 us; speedup 1.0000x reference)
//
#include <hip/hip_runtime.h>
#include <math.h>

#define RR 64
#define DD 256
#define CAP 6144

// ---------- helpers ----------

__device__ __forceinline__ void get_mu_istd(const double* sums, int N, float& fmu, float& istd) {
  double M = (double)RR * (double)N;
  double mu = sums[0] / M;
  double var = (sums[1] - sums[0] * sums[0] / M) / (M - 1.0);
  fmu = (float)mu;
  istd = (float)(1.0 / sqrt(var));
}

// monotone float<->uint mapping for atomicMax on signed floats
__device__ __forceinline__ unsigned fmap(float f) {
  unsigned b = __float_as_uint(f);
  return (b & 0x80000000u) ? ~b : (b | 0x80000000u);
}
__device__ __forceinline__ float funmap(unsigned u) {
  unsigned b = (u & 0x80000000u) ? (u & 0x7fffffffu) : ~u;
  return __uint_as_float(b);
}

// ---------- K_mask: per-block dtype sniff (same 4KB window -> consistent) + pack ----------

__global__ __launch_bounds__(256) void k_mask(const void* __restrict__ maskp,
                                              unsigned long long* __restrict__ mbits,
                                              int N) {
  __shared__ int f;
  int tid = threadIdx.x;
  if (tid == 0) f = 0;
  __syncthreads();
  {
    const unsigned* mw = (const unsigned*)maskp;
    int mode = 0;
    for (int i = tid; i < 4096; i += 256) {
      unsigned v = mw[i];
      if (v == 0x3f800000u) mode = 2;
      else if (v > 1u && mode != 2) mode = 1;
    }
    if (mode) atomicMax(&f, mode);
  }
  __syncthreads();
  const int mode = f;

  int n = blockIdx.x * 256 + tid;
  if (n >= N) return;
  unsigned long long b = 0;
  if (mode == 1) {
    const unsigned char* m = (const unsigned char*)maskp;
#pragma unroll
    for (int r = 0; r < RR; ++r)
      b |= (unsigned long long)(m[(size_t)r * N + n] != 0) << r;
  } else if (mode == 2) {
    const float* m = (const float*)maskp;
#pragma unroll
    for (int r = 0; r < RR; ++r)
      b |= (unsigned long long)(m[(size_t)r * N + n] != 0.f) << r;
  } else {
    const int* m = (const int*)maskp;
#pragma unroll
    for (int r = 0; r < RR; ++r)
      b |= (unsigned long long)(m[(size_t)r * N + n] != 0) << r;
  }
  mbits[n] = b;
}

// ---------- K1: hsW = hs @ W   [64 x 256] ----------

__global__ __launch_bounds__(256) void k_hsw(const float* __restrict__ hs,
                                             const float* __restrict__ W,
                                             float* __restrict__ hsW) {
  int i = blockIdx.x;
  int j = threadIdx.x;
  float acc = 0.f;
  for (int k = 0; k < DD; ++k) acc = fmaf(hs[i * DD + k], W[k * DD + j], acc);
  hsW[i * DD + j] = acc;
}

// ---------- K2: scores GEMM ----------
// Round-7: round-0 structure restored (it had the right cache behavior:
// FETCH ~100MB), but tile narrowed 256->128 cols/block. The round-0 limiter
// was GRID starvation: 782 blocks = 3.05 blocks/CU, barrier-synced waves with
// nothing to hide latency behind (VALUBusy 19%, occupancy 15.6%). 1563 blocks
// -> 6 blocks/CU; acc shrinks 64->32 VGPR so __launch_bounds__(256,6) fits
// without spill -> ~24 waves/CU of cross-block overlap.
// Round-1's global_load_lds 64B-granule staging is REVERTED (it tripled HBM
// traffic: 64B pieces of 128B lines thrashed L2 -> FETCH 101->268MB).
// Accumulation order per (row,col) identical to round-0 -> bitwise-same scores.

__global__ __launch_bounds__(256, 6) void k_scores(const float* __restrict__ es,
                                                   const float* __restrict__ hsW,
                                                   const unsigned long long* __restrict__ mbits,
                                                   float* __restrict__ scores,
                                                   float* __restrict__ colmax,
                                                   int* __restrict__ colargmax,
                                                   double* __restrict__ sums,
                                                   unsigned* __restrict__ rowmax_u,
                                                   int N) {
  __shared__ float lds[128 * 36];   // es tile [col][36]; reused as stat buffer
  __shared__ float wlds[64 * 32];   // hsW chunk [row][32]
  __shared__ double red[8];
  const int tid = threadIdx.x;
  const int lane = tid & 63;
  const int ty = __builtin_amdgcn_readfirstlane(tid >> 6);
  const int n0 = blockIdx.x * 128;
  const int R0 = ty * 16;
  const int nb = n0 + lane;    // col c -> nb + 64*c, c in {0,1}

  float2 acc[16];
#pragma unroll
  for (int i = 0; i < 16; ++i) acc[i] = make_float2(0.f, 0.f);

  for (int kc = 0; kc < DD; kc += 32) {
    __syncthreads();
    // stage es tile (16 KB): 128 cols x 32 k
#pragma unroll
    for (int p = 0; p < 4; ++p) {
      int c = p * 32 + (tid >> 3);
      int rr = min(n0 + c, N - 1);
      const float4 v = *(const float4*)(es + (size_t)rr * DD + kc + (tid & 7) * 4);
      *(float4*)(lds + c * 36 + (tid & 7) * 4) = v;
    }
    // stage hsW chunk (8 KB): thread -> row tid/4, k' (tid%4)*8 .. +8
    {
      int wrow = tid >> 2;
      int wk = (tid & 3) * 8;
      const float4 a = *(const float4*)(hsW + wrow * DD + kc + wk);
      const float4 b = *(const float4*)(hsW + wrow * DD + kc + wk + 4);
      *(float4*)(wlds + wrow * 32 + wk) = a;
      *(float4*)(wlds + wrow * 32 + wk + 4) = b;
    }
    __syncthreads();
#pragma unroll
    for (int k = 0; k < 32; k += 4) {
      const float4 e0 = *(const float4*)(lds + (lane +  0) * 36 + k);
      const float4 e1 = *(const float4*)(lds + (lane + 64) * 36 + k);
#pragma unroll
      for (int i = 0; i < 16; ++i) {
        const float4 w = *(const float4*)(wlds + (R0 + i) * 32 + k);  // uniform -> broadcast
        acc[i].x = fmaf(w.x, e0.x, fmaf(w.y, e0.y, fmaf(w.z, e0.z, fmaf(w.w, e0.w, acc[i].x))));
        acc[i].y = fmaf(w.x, e1.x, fmaf(w.y, e1.y, fmaf(w.z, e1.z, fmaf(w.w, e1.w, acc[i].y))));
      }
    }
  }

  // ---- col validity ----
  bool val[2];
#pragma unroll
  for (int c = 0; c < 2; ++c) val[c] = (nb + 64 * c) < N;

  // ---- store scores ----
#pragma unroll
  for (int i = 0; i < 16; ++i) {
    float* dst = scores + (size_t)(R0 + i) * N + nb;
    float v[2] = {acc[i].x, acc[i].y};
#pragma unroll
    for (int c = 0; c < 2; ++c)
      if (val[c]) dst[64 * c] = v[c];
  }

  // ---- mask bits for my 2 cols ----
  unsigned long long mb[2];
#pragma unroll
  for (int c = 0; c < 2; ++c) mb[c] = val[c] ? mbits[nb + 64 * c] : 0ull;

  // ---- per-col partials over my 16 rows + fused row-max reductions ----
  float ps1[2], ps2[2], pcm[2], pbv[2];
  int pbr[2];
#pragma unroll
  for (int c = 0; c < 2; ++c) { ps1[c] = 0.f; ps2[c] = 0.f; pcm[c] = -INFINITY; pbv[c] = -INFINITY; pbr[c] = -1; }

#pragma unroll
  for (int i = 0; i < 16; ++i) {
    const int rrow = R0 + i;
    float v[2] = {acc[i].x, acc[i].y};
    float q = -INFINITY, qm = -INFINITY;
#pragma unroll
    for (int c = 0; c < 2; ++c) {
      ps1[c] += v[c];
      ps2[c] = fmaf(v[c], v[c], ps2[c]);
      pcm[c] = fmaxf(pcm[c], v[c]);
      bool bit = (mb[c] >> rrow) & 1ull;
      if (bit && (v[c] > pbv[c])) { pbv[c] = v[c]; pbr[c] = rrow; }
      float qv = val[c] ? v[c] : -INFINITY;
      q = fmaxf(q, qv);
      if (bit) qm = fmaxf(qm, qv);
    }
#pragma unroll
    for (int o = 32; o > 0; o >>= 1) {
      q = fmaxf(q, __shfl_down(q, o));
      qm = fmaxf(qm, __shfl_down(qm, o));
    }
    if (lane == 0) {
      atomicMax(rowmax_u + rrow, fmap(q));
      atomicMax(rowmax_u + 64 + rrow, fmap(qm));
    }
  }

  // ---- cross-wave col-stat combine via LDS (reuse es tile region) ----
  __syncthreads();   // done with es tile
  float* Ls1 = lds;
  float* Ls2 = lds + 512;
  float* Lcm = lds + 1024;
  float* Lbv = lds + 1536;
  int* Lbr = (int*)(lds + 2048);
#pragma unroll
  for (int c = 0; c < 2; ++c) {
    int col = lane + 64 * c;
    Ls1[ty * 128 + col] = ps1[c];
    Ls2[ty * 128 + col] = ps2[c];
    Lcm[ty * 128 + col] = pcm[c];
    Lbv[ty * 128 + col] = pbv[c];
    Lbr[ty * 128 + col] = pbr[c];
  }
  __syncthreads();

  float s1 = 0.f, s2 = 0.f;
  if (tid < 128) {
    const int n = n0 + tid;
    if (n < N) {
      s1 = Ls1[tid] + Ls1[128 + tid] + Ls1[256 + tid] + Ls1[384 + tid];
      s2 = Ls2[tid] + Ls2[128 + tid] + Ls2[256 + tid] + Ls2[384 + tid];
      float cm = fmaxf(fmaxf(Lcm[tid], Lcm[128 + tid]), fmaxf(Lcm[256 + tid], Lcm[384 + tid]));
      colmax[n] = cm;
      float bv = -INFINITY;
      int br = -1;
#pragma unroll
      for (int w2 = 0; w2 < 4; ++w2) {
        float b = Lbv[w2 * 128 + tid];
        if (b > bv) { bv = b; br = Lbr[w2 * 128 + tid]; }
      }
      colargmax[n] = br;
    }
  }

  double d1 = (double)s1, d2 = (double)s2;
#pragma unroll
  for (int o = 32; o > 0; o >>= 1) {
    d1 += __shfl_down(d1, o);
    d2 += __shfl_down(d2, o);
  }
  if ((tid & 63) == 0) { red[ty * 2] = d1; red[ty * 2 + 1] = d2; }
  __syncthreads();
  if (tid == 0) {
    atomicAdd(&sums[0], red[0] + red[2] + red[4] + red[6]);
    atomicAdd(&sums[1], red[1] + red[3] + red[5] + red[7]);
  }
}

// ---------- K4: fused column pass: collse + row exp-sums + candidate scatter ----------
// Round-7: exp factorization. exp((x-m_r)*istd) = E * exp((gm-m_r)*istd) with
// E = exp((x-gm)*istd), gm = global rowmax. 3 expf/element -> 1 expf/element;
// per-row scales applied once after the reduction. Exponent (x-gm)*istd is in
// [-~11, 0] for standardized scores -> no under/overflow.

__global__ __launch_bounds__(256) void k_colpass(const float* __restrict__ scores,
                                                 const float* __restrict__ colmax,
                                                 const int* __restrict__ colargmax,
                                                 const unsigned long long* __restrict__ mbits,
                                                 const double* __restrict__ sums,
                                                 const unsigned* __restrict__ rowmax_u,
                                                 float* __restrict__ collse,
                                                 float* __restrict__ rowacc,
                                                 int* __restrict__ cnt,
                                                 float* __restrict__ candx,
                                                 int* __restrict__ candn,
                                                 int N) {
  __shared__ float rmS[64], suS[64], smS[64];
  __shared__ float rpu[64 * 4], rpm[64 * 4];
  __shared__ int lcnt[64], lbase[64];
  const int tid = threadIdx.x, lane = tid & 63, ty = tid >> 6;
  float fmu, istd;
  get_mu_istd(sums, N, fmu, istd);
  if (tid < 64) {
    rmS[tid] = funmap(rowmax_u[tid]);
    lcnt[tid] = 0;
  }
  __syncthreads();
  // every thread computes gm (uniform LDS broadcasts, cheap)
  float gm = rmS[0];
#pragma unroll
  for (int r = 1; r < RR; ++r) gm = fmaxf(gm, rmS[r]);
  if (tid < 64) {
    suS[tid] = expf((gm - rmS[tid]) * istd);
    smS[tid] = expf((gm - funmap(rowmax_u[64 + tid])) * istd);
  }
  // suS/smS consumed only after the later __syncthreads()

  const int n = blockIdx.x * 256 + tid;
  const bool valid = n < N;
  const float cm = valid ? colmax[n] : 0.f;
  const int br = valid ? colargmax[n] : -1;
  const unsigned long long mbn = valid ? mbits[n] : 0ull;
  float colsum = 0.f, xbr = 0.f;

  for (int r = 0; r < RR; ++r) {
    float x = valid ? scores[(size_t)r * N + n] : 0.f;
    if (r == br) xbr = x;
    float E = valid ? expf((x - gm) * istd) : 0.f;
    colsum += E;
    float eu = E;
    float em = ((mbn >> r) & 1ull) ? E : 0.f;
#pragma unroll
    for (int o = 32; o > 0; o >>= 1) {
      eu += __shfl_down(eu, o);
      em += __shfl_down(em, o);
    }
    if (lane == 0) { rpu[r * 4 + ty] = eu; rpm[r * 4 + ty] = em; }
  }

  if (valid) collse[n] = logf(colsum) + (gm - cm) * istd;
  int lpos = 0;
  if (br >= 0) lpos = atomicAdd(&lcnt[br], 1);
  __syncthreads();
  if (tid < 64) {
    float su = (rpu[tid * 4] + rpu[tid * 4 + 1] + rpu[tid * 4 + 2] + rpu[tid * 4 + 3]) * suS[tid];
    float sm = (rpm[tid * 4] + rpm[tid * 4 + 1] + rpm[tid * 4 + 2] + rpm[tid * 4 + 3]) * smS[tid];
    atomicAdd(&rowacc[tid], su);
    atomicAdd(&rowacc[64 + tid], sm);
    int c = lcnt[tid];
    lbase[tid] = c ? atomicAdd(&cnt[tid], c) : 0;
  }
  __syncthreads();
  if (br >= 0) {
    int pos = lbase[br] + lpos;
    if (pos < CAP) {
      candx[(size_t)br * CAP + pos] = xbr;
      candn[(size_t)br * CAP + pos] = n;
    }
  }
}

// ---------- K3b: finalize row stats ----------

__global__ void k_rowfin(const float* __restrict__ rowacc,
                         const unsigned* __restrict__ rowmax_u,
                         float* __restrict__ rowstats) {
  int r = threadIdx.x;  // 64
  rowstats[r] = funmap(rowmax_u[r]);
  rowstats[64 + r] = logf(rowacc[r]);
  rowstats[128 + r] = funmap(rowmax_u[64 + r]);
  rowstats[192 + r] = rowacc[64 + r];
}

// ---------- K5: per-row top-50 (prob desc, index asc), 512 threads ----------

__global__ __launch_bounds__(512) void k_topk(const int* __restrict__ cnt,
                                              const float* __restrict__ candx,
                                              const int* __restrict__ candn,
                                              const double* __restrict__ sums,
                                              const float* __restrict__ rowstats,
                                              float* __restrict__ out,
                                              int* __restrict__ seln,
                                              int N, int NO) {
  int r = blockIdx.x, tid = threadIdx.x;
  __shared__ float sp[CAP];
  __shared__ int sn[CAP];
  __shared__ float wp[8];
  __shared__ int wn[8], wi[8];
  int c = min(cnt[r], CAP);
  float fmu, istd;
  get_mu_istd(sums, N, fmu, istd);
  const float rmm = rowstats[128 + r];
  const float lm = rowstats[192 + r];
  for (int i = tid; i < c; i += 512) {
    float xv = candx[(size_t)r * CAP + i];
    sp[i] = fmaxf(expf((xv - rmm) * istd) / lm, 1e-6f);
    sn[i] = candn[(size_t)r * CAP + i];
  }
  __syncthreads();
  for (int j = 0; j < NO; ++j) {
    float bp = -1.f;
    int bn = 0x7fffffff, bi = -1;
    for (int i = tid; i < c; i += 512) {
      float p = sp[i];
      int nn = sn[i];
      if (p > bp || (p == bp && nn < bn)) { bp = p; bn = nn; bi = i; }
    }
#pragma unroll
    for (int o = 32; o > 0; o >>= 1) {
      float p2 = __shfl_down(bp, o);
      int n2 = __shfl_down(bn, o);
      int i2 = __shfl_down(bi, o);
      if (p2 > bp || (p2 == bp && n2 < bn)) { bp = p2; bn = n2; bi = i2; }
    }
    if ((tid & 63) == 0) { wp[tid >> 6] = bp; wn[tid >> 6] = bn; wi[tid >> 6] = bi; }
    __syncthreads();
    if (tid == 0) {
      float fp2 = wp[0]; int fn2 = wn[0], fi2 = wi[0];
#pragma unroll
      for (int w2 = 1; w2 < 8; ++w2) {
        if (wp[w2] > fp2 || (wp[w2] == fp2 && wn[w2] < fn2)) { fp2 = wp[w2]; fn2 = wn[w2]; fi2 = wi[w2]; }
      }
      if (fp2 > 0.f) {
        out[r * NO + j] = (float)fn2;
        seln[r * NO + j] = fn2;
        sp[fi2] = -1.f;
      } else {
        out[r * NO + j] = -1.f;
        seln[r * NO + j] = -1;
      }
    }
    __syncthreads();
  }
}

// ---------- K6: exp_scores ----------

__global__ void k_expand(const float* __restrict__ scores,
                         const double* __restrict__ sums,
                         const float* __restrict__ rowstats,
                         const float* __restrict__ colmax,
                         const float* __restrict__ collse,
                         const int* __restrict__ seln,
                         float* __restrict__ out,
                         int N, int NO) {
  int b = blockIdx.x;
  int r2 = threadIdx.x;
  int n = seln[b];
  float v = 0.f;
  if (n >= 0) {
    float fmu, istd;
    get_mu_istd(sums, N, fmu, istd);
    float x = scores[(size_t)r2 * N + n];
    float v1 = (x - rowstats[r2]) * istd - rowstats[64 + r2];
    float v2 = (x - colmax[n]) * istd - collse[n];
    v = v1 + v2;
  }
  out[RR * NO + (size_t)b * RR + r2] = v;
}

// ---------- launch ----------

extern "C" void kernel_launch(void* const* d_in, const int* in_sizes, int n_in,
                              void* d_out, int out_size, void* d_ws, size_t ws_size,
                              hipStream_t stream) {
  const float* hs = (const float*)d_in[0];
  const float* es = (const float*)d_in[1];
  const float* W = (const float*)d_in[2];
  const void* mask = d_in[3];

  const int N = in_sizes[1] / DD;               // 200000
  const int NO = out_size / (RR * (1 + RR));    // 50

  char* ws = (char*)d_ws;
  size_t o = 0;
  float* scores = (float*)(ws + o);   o += (size_t)RR * N * 4;
  float* hsW = (float*)(ws + o);      o += RR * DD * 4;
  o = (o + 255) & ~(size_t)255;
  // contiguous zero region: sums(16) + cnt(256) + rowmax_u(512) + rowacc(512)
  double* sums = (double*)(ws + o);
  int* cnt = (int*)(ws + o + 16);
  unsigned* rowmax_u = (unsigned*)(ws + o + 16 + 256);
  float* rowacc = (float*)(ws + o + 16 + 256 + 512);
  size_t zero_off = o, zero_bytes = 16 + 256 + 512 + 512;
  o += 1536;
  float* rowstats = (float*)(ws + o); o += 256 * 4;
  o = (o + 255) & ~(size_t)255;
  float* colmax = (float*)(ws + o);   o += (size_t)N * 4;
  int* colargmax = (int*)(ws + o);    o += (size_t)N * 4;
  float* collse = (float*)(ws + o);   o += (size_t)N * 4;
  o = (o + 255) & ~(size_t)255;
  unsigned long long* mbits = (unsigned long long*)(ws + o); o += (size_t)N * 8;
  o = (o + 255) & ~(size_t)255;
  float* candx = (float*)(ws + o);    o += (size_t)RR * CAP * 4;
  int* candn = (int*)(ws + o);        o += (size_t)RR * CAP * 4;
  int* seln = (int*)(ws + o);         o += (size_t)RR * NO * 4;

  hipMemsetAsync(ws + zero_off, 0, zero_bytes, stream);

  const int NB = (N + 255) / 256;     // 256-col blocks (mask/colpass)
  const int NBS = (N + 127) / 128;    // 128-col blocks (scores)

  k_mask<<<NB, 256, 0, stream>>>(mask, mbits, N);
  k_hsw<<<RR, 256, 0, stream>>>(hs, W, hsW);
  k_scores<<<NBS, 256, 0, stream>>>(es, hsW, mbits, scores, colmax, colargmax, sums,
                                    rowmax_u, N);
  k_colpass<<<NB, 256, 0, stream>>>(scores, colmax, colargmax, mbits, sums, rowmax_u,
                                    collse, rowacc, cnt, candx, candn, N);
  k_rowfin<<<1, 64, 0, stream>>>(rowacc, rowmax_u, rowstats);
  k_topk<<<RR, 512, 0, stream>>>(cnt, candx, candn, sums, rowstats, (float*)d_out, seln,
                                 N, NO);
  k_expand<<<RR * NO, 64, 0, stream>>>(scores, sums, rowstats, colmax, collse, seln,
                                       (float*)d_out, N, NO);
}

// Round 3
// 1111.910 us; speedup vs baseline: 1.7729x; 1.7729x over previous
//
#include <hip/hip_runtime.h>
#include <math.h>

#define RR 64
#define DD 256
#define CAP 6144

// ---------- helpers ----------

__device__ __forceinline__ void get_mu_istd(const double* sums, int N, float& fmu, float& istd) {
  double M = (double)RR * (double)N;
  double mu = sums[0] / M;
  double var = (sums[1] - sums[0] * sums[0] / M) / (M - 1.0);
  fmu = (float)mu;
  istd = (float)(1.0 / sqrt(var));
}

// monotone float<->uint mapping for atomicMax on signed floats
__device__ __forceinline__ unsigned fmap(float f) {
  unsigned b = __float_as_uint(f);
  return (b & 0x80000000u) ? ~b : (b | 0x80000000u);
}
__device__ __forceinline__ float funmap(unsigned u) {
  unsigned b = (u & 0x80000000u) ? (u & 0x7fffffffu) : ~u;
  return __uint_as_float(b);
}

// ---------- K_mask: per-block dtype sniff (same 4KB window -> consistent) + pack ----------

__global__ __launch_bounds__(256) void k_mask(const void* __restrict__ maskp,
                                              unsigned long long* __restrict__ mbits,
                                              int N) {
  __shared__ int f;
  int tid = threadIdx.x;
  if (tid == 0) f = 0;
  __syncthreads();
  {
    const unsigned* mw = (const unsigned*)maskp;
    int mode = 0;
    for (int i = tid; i < 4096; i += 256) {
      unsigned v = mw[i];
      if (v == 0x3f800000u) mode = 2;
      else if (v > 1u && mode != 2) mode = 1;
    }
    if (mode) atomicMax(&f, mode);
  }
  __syncthreads();
  const int mode = f;

  int n = blockIdx.x * 256 + tid;
  if (n >= N) return;
  unsigned long long b = 0;
  if (mode == 1) {
    const unsigned char* m = (const unsigned char*)maskp;
#pragma unroll
    for (int r = 0; r < RR; ++r)
      b |= (unsigned long long)(m[(size_t)r * N + n] != 0) << r;
  } else if (mode == 2) {
    const float* m = (const float*)maskp;
#pragma unroll
    for (int r = 0; r < RR; ++r)
      b |= (unsigned long long)(m[(size_t)r * N + n] != 0.f) << r;
  } else {
    const int* m = (const int*)maskp;
#pragma unroll
    for (int r = 0; r < RR; ++r)
      b |= (unsigned long long)(m[(size_t)r * N + n] != 0) << r;
  }
  mbits[n] = b;
}

// ---------- K1: hsW = hs @ W   [64 x 256] ----------

__global__ __launch_bounds__(256) void k_hsw(const float* __restrict__ hs,
                                             const float* __restrict__ W,
                                             float* __restrict__ hsW) {
  int i = blockIdx.x;
  int j = threadIdx.x;
  float acc = 0.f;
  for (int k = 0; k < DD; ++k) acc = fmaf(hs[i * DD + k], W[k * DD + j], acc);
  hsW[i * DD + j] = acc;
}

// ---------- K2: scores GEMM ----------
// Round-8: column-owner register design. Each thread owns ONE column n:
//  - streams its own es row in 8x float4 per 32-k chunk (one pass per 128B
//    line -> round-0 cache behavior preserved);
//  - all 64 accumulators in VGPRs;
//  - hsW operand is wave-uniform (r,k loop constants) -> s_load + SGPR operand
//    into v_fmac (1 SGPR/VALU legal).
// => NO LDS, NO barriers in the hot loop. Waves free-run; latency hidden by
// TLP + s_load pipelining. This removes the barrier-phase stall that held
// round 0 at VALUBusy 19% (wall 5x the VALU floor).
// Round-2 lesson applied: NO min-waves launch_bounds (the (256,6) forced
// VGPR=40 -> acc spilled to scratch -> 3.7GB scratch writes).
// Numerics: fmaf nesting reproduces round-0's exact accumulation order
// (per 4-group: k+3,k+2,k+1,k+0; groups/chunks ascending) -> bitwise-identical
// scores -> identical selection. colargmax tie-break (ascending r, strict >)
// preserved.

__global__ __launch_bounds__(256) void k_scores(const float* __restrict__ es,
                                                const float* __restrict__ hsW,
                                                const unsigned long long* __restrict__ mbits,
                                                float* __restrict__ scores,
                                                float* __restrict__ colmax,
                                                int* __restrict__ colargmax,
                                                double* __restrict__ sums,
                                                unsigned* __restrict__ rowmax_u,
                                                int N) {
  __shared__ float qb[64 * 4], qmb[64 * 4];
  __shared__ double red[8];
  const int tid = threadIdx.x;
  const int lane = tid & 63;
  const int ty = tid >> 6;
  const int n = blockIdx.x * 256 + tid;
  const bool valid = n < N;
  const int nc = valid ? n : N - 1;
  const float* erow = es + (size_t)nc * DD;

  float acc[64];
#pragma unroll
  for (int r = 0; r < 64; ++r) acc[r] = 0.f;

  for (int kc = 0; kc < DD; kc += 32) {   // 8 chunks, body ~2k inst (fits I$)
    float4 e[8];
#pragma unroll
    for (int u = 0; u < 8; ++u) e[u] = *(const float4*)(erow + kc + u * 4);
#pragma unroll
    for (int r = 0; r < 64; ++r) {
      const float* hw = hsW + r * DD + kc;   // uniform address -> s_load
      float a = acc[r];
#pragma unroll
      for (int u = 0; u < 8; ++u) {
        const float4 w = *(const float4*)(hw + u * 4);
        const float4 ev = e[u];
        a = fmaf(w.x, ev.x, fmaf(w.y, ev.y, fmaf(w.z, ev.z, fmaf(w.w, ev.w, a))));
      }
      acc[r] = a;
    }
  }

  // ---- store scores (coalesced 256B per wave per row) ----
#pragma unroll
  for (int r = 0; r < 64; ++r)
    if (valid) scores[(size_t)r * N + n] = acc[r];

  // ---- thread-local column stats ----
  const unsigned long long mb = valid ? mbits[n] : 0ull;
  float cm = -INFINITY, bv = -INFINITY;
  int br = -1;
  float s1f = 0.f, s2f = 0.f;
#pragma unroll
  for (int r = 0; r < 64; ++r) {
    float v = acc[r];
    s1f += v;
    s2f = fmaf(v, v, s2f);
    cm = fmaxf(cm, v);
    bool bit = (mb >> r) & 1ull;
    if (bit && v > bv) { bv = v; br = r; }
  }
  if (!valid) { s1f = 0.f; s2f = 0.f; }
  if (valid) { colmax[n] = cm; colargmax[n] = br; }

  // ---- row maxes: wave shfl reduce per row, then block combine via LDS ----
#pragma unroll
  for (int r = 0; r < 64; ++r) {
    float q = valid ? acc[r] : -INFINITY;
    float qm2 = ((mb >> r) & 1ull) ? q : -INFINITY;
#pragma unroll
    for (int o = 32; o > 0; o >>= 1) {
      q = fmaxf(q, __shfl_down(q, o));
      qm2 = fmaxf(qm2, __shfl_down(qm2, o));
    }
    if (lane == 0) { qb[r * 4 + ty] = q; qmb[r * 4 + ty] = qm2; }
  }

  // ---- sums (double wave reduce + LDS combine) ----
  double d1 = (double)s1f, d2 = (double)s2f;
#pragma unroll
  for (int o = 32; o > 0; o >>= 1) {
    d1 += __shfl_down(d1, o);
    d2 += __shfl_down(d2, o);
  }
  if (lane == 0) { red[ty * 2] = d1; red[ty * 2 + 1] = d2; }
  __syncthreads();
  if (tid < 64) {
    float q = fmaxf(fmaxf(qb[tid * 4], qb[tid * 4 + 1]), fmaxf(qb[tid * 4 + 2], qb[tid * 4 + 3]));
    float qm2 = fmaxf(fmaxf(qmb[tid * 4], qmb[tid * 4 + 1]), fmaxf(qmb[tid * 4 + 2], qmb[tid * 4 + 3]));
    atomicMax(rowmax_u + tid, fmap(q));
    atomicMax(rowmax_u + 64 + tid, fmap(qm2));
  }
  if (tid == 0) {
    atomicAdd(&sums[0], red[0] + red[2] + red[4] + red[6]);
    atomicAdd(&sums[1], red[1] + red[3] + red[5] + red[7]);
  }
}

// ---------- K4: fused column pass: collse + row exp-sums + candidate scatter ----------
// exp factorization (round-7, verified): exp((x-m_r)*istd) = E * exp((gm-m_r)*istd)
// with E = exp((x-gm)*istd), gm = global rowmax. 1 expf/element.

__global__ __launch_bounds__(256) void k_colpass(const float* __restrict__ scores,
                                                 const float* __restrict__ colmax,
                                                 const int* __restrict__ colargmax,
                                                 const unsigned long long* __restrict__ mbits,
                                                 const double* __restrict__ sums,
                                                 const unsigned* __restrict__ rowmax_u,
                                                 float* __restrict__ collse,
                                                 float* __restrict__ rowacc,
                                                 int* __restrict__ cnt,
                                                 float* __restrict__ candx,
                                                 int* __restrict__ candn,
                                                 int N) {
  __shared__ float rmS[64], suS[64], smS[64];
  __shared__ float rpu[64 * 4], rpm[64 * 4];
  __shared__ int lcnt[64], lbase[64];
  const int tid = threadIdx.x, lane = tid & 63, ty = tid >> 6;
  float fmu, istd;
  get_mu_istd(sums, N, fmu, istd);
  if (tid < 64) {
    rmS[tid] = funmap(rowmax_u[tid]);
    lcnt[tid] = 0;
  }
  __syncthreads();
  // every thread computes gm (uniform LDS broadcasts, cheap)
  float gm = rmS[0];
#pragma unroll
  for (int r = 1; r < RR; ++r) gm = fmaxf(gm, rmS[r]);
  if (tid < 64) {
    suS[tid] = expf((gm - rmS[tid]) * istd);
    smS[tid] = expf((gm - funmap(rowmax_u[64 + tid])) * istd);
  }
  // suS/smS consumed only after the later __syncthreads()

  const int n = blockIdx.x * 256 + tid;
  const bool valid = n < N;
  const float cm = valid ? colmax[n] : 0.f;
  const int br = valid ? colargmax[n] : -1;
  const unsigned long long mbn = valid ? mbits[n] : 0ull;
  float colsum = 0.f, xbr = 0.f;

  for (int r = 0; r < RR; ++r) {
    float x = valid ? scores[(size_t)r * N + n] : 0.f;
    if (r == br) xbr = x;
    float E = valid ? expf((x - gm) * istd) : 0.f;
    colsum += E;
    float eu = E;
    float em = ((mbn >> r) & 1ull) ? E : 0.f;
#pragma unroll
    for (int o = 32; o > 0; o >>= 1) {
      eu += __shfl_down(eu, o);
      em += __shfl_down(em, o);
    }
    if (lane == 0) { rpu[r * 4 + ty] = eu; rpm[r * 4 + ty] = em; }
  }

  if (valid) collse[n] = logf(colsum) + (gm - cm) * istd;
  int lpos = 0;
  if (br >= 0) lpos = atomicAdd(&lcnt[br], 1);
  __syncthreads();
  if (tid < 64) {
    float su = (rpu[tid * 4] + rpu[tid * 4 + 1] + rpu[tid * 4 + 2] + rpu[tid * 4 + 3]) * suS[tid];
    float sm = (rpm[tid * 4] + rpm[tid * 4 + 1] + rpm[tid * 4 + 2] + rpm[tid * 4 + 3]) * smS[tid];
    atomicAdd(&rowacc[tid], su);
    atomicAdd(&rowacc[64 + tid], sm);
    int c = lcnt[tid];
    lbase[tid] = c ? atomicAdd(&cnt[tid], c) : 0;
  }
  __syncthreads();
  if (br >= 0) {
    int pos = lbase[br] + lpos;
    if (pos < CAP) {
      candx[(size_t)br * CAP + pos] = xbr;
      candn[(size_t)br * CAP + pos] = n;
    }
  }
}

// ---------- K3b: finalize row stats ----------

__global__ void k_rowfin(const float* __restrict__ rowacc,
                         const unsigned* __restrict__ rowmax_u,
                         float* __restrict__ rowstats) {
  int r = threadIdx.x;  // 64
  rowstats[r] = funmap(rowmax_u[r]);
  rowstats[64 + r] = logf(rowacc[r]);
  rowstats[128 + r] = funmap(rowmax_u[64 + r]);
  rowstats[192 + r] = rowacc[64 + r];
}

// ---------- K5: per-row top-50 (prob desc, index asc), 512 threads ----------

__global__ __launch_bounds__(512) void k_topk(const int* __restrict__ cnt,
                                              const float* __restrict__ candx,
                                              const int* __restrict__ candn,
                                              const double* __restrict__ sums,
                                              const float* __restrict__ rowstats,
                                              float* __restrict__ out,
                                              int* __restrict__ seln,
                                              int N, int NO) {
  int r = blockIdx.x, tid = threadIdx.x;
  __shared__ float sp[CAP];
  __shared__ int sn[CAP];
  __shared__ float wp[8];
  __shared__ int wn[8], wi[8];
  int c = min(cnt[r], CAP);
  float fmu, istd;
  get_mu_istd(sums, N, fmu, istd);
  const float rmm = rowstats[128 + r];
  const float lm = rowstats[192 + r];
  for (int i = tid; i < c; i += 512) {
    float xv = candx[(size_t)r * CAP + i];
    sp[i] = fmaxf(expf((xv - rmm) * istd) / lm, 1e-6f);
    sn[i] = candn[(size_t)r * CAP + i];
  }
  __syncthreads();
  for (int j = 0; j < NO; ++j) {
    float bp = -1.f;
    int bn = 0x7fffffff, bi = -1;
    for (int i = tid; i < c; i += 512) {
      float p = sp[i];
      int nn = sn[i];
      if (p > bp || (p == bp && nn < bn)) { bp = p; bn = nn; bi = i; }
    }
#pragma unroll
    for (int o = 32; o > 0; o >>= 1) {
      float p2 = __shfl_down(bp, o);
      int n2 = __shfl_down(bn, o);
      int i2 = __shfl_down(bi, o);
      if (p2 > bp || (p2 == bp && n2 < bn)) { bp = p2; bn = n2; bi = i2; }
    }
    if ((tid & 63) == 0) { wp[tid >> 6] = bp; wn[tid >> 6] = bn; wi[tid >> 6] = bi; }
    __syncthreads();
    if (tid == 0) {
      float fp2 = wp[0]; int fn2 = wn[0], fi2 = wi[0];
#pragma unroll
      for (int w2 = 1; w2 < 8; ++w2) {
        if (wp[w2] > fp2 || (wp[w2] == fp2 && wn[w2] < fn2)) { fp2 = wp[w2]; fn2 = wn[w2]; fi2 = wi[w2]; }
      }
      if (fp2 > 0.f) {
        out[r * NO + j] = (float)fn2;
        seln[r * NO + j] = fn2;
        sp[fi2] = -1.f;
      } else {
        out[r * NO + j] = -1.f;
        seln[r * NO + j] = -1;
      }
    }
    __syncthreads();
  }
}

// ---------- K6: exp_scores ----------

__global__ void k_expand(const float* __restrict__ scores,
                         const double* __restrict__ sums,
                         const float* __restrict__ rowstats,
                         const float* __restrict__ colmax,
                         const float* __restrict__ collse,
                         const int* __restrict__ seln,
                         float* __restrict__ out,
                         int N, int NO) {
  int b = blockIdx.x;
  int r2 = threadIdx.x;
  int n = seln[b];
  float v = 0.f;
  if (n >= 0) {
    float fmu, istd;
    get_mu_istd(sums, N, fmu, istd);
    float x = scores[(size_t)r2 * N + n];
    float v1 = (x - rowstats[r2]) * istd - rowstats[64 + r2];
    float v2 = (x - colmax[n]) * istd - collse[n];
    v = v1 + v2;
  }
  out[RR * NO + (size_t)b * RR + r2] = v;
}

// ---------- launch ----------

extern "C" void kernel_launch(void* const* d_in, const int* in_sizes, int n_in,
                              void* d_out, int out_size, void* d_ws, size_t ws_size,
                              hipStream_t stream) {
  const float* hs = (const float*)d_in[0];
  const float* es = (const float*)d_in[1];
  const float* W = (const float*)d_in[2];
  const void* mask = d_in[3];

  const int N = in_sizes[1] / DD;               // 200000
  const int NO = out_size / (RR * (1 + RR));    // 50

  char* ws = (char*)d_ws;
  size_t o = 0;
  float* scores = (float*)(ws + o);   o += (size_t)RR * N * 4;
  float* hsW = (float*)(ws + o);      o += RR * DD * 4;
  o = (o + 255) & ~(size_t)255;
  // contiguous zero region: sums(16) + cnt(256) + rowmax_u(512) + rowacc(512)
  double* sums = (double*)(ws + o);
  int* cnt = (int*)(ws + o + 16);
  unsigned* rowmax_u = (unsigned*)(ws + o + 16 + 256);
  float* rowacc = (float*)(ws + o + 16 + 256 + 512);
  size_t zero_off = o, zero_bytes = 16 + 256 + 512 + 512;
  o += 1536;
  float* rowstats = (float*)(ws + o); o += 256 * 4;
  o = (o + 255) & ~(size_t)255;
  float* colmax = (float*)(ws + o);   o += (size_t)N * 4;
  int* colargmax = (int*)(ws + o);    o += (size_t)N * 4;
  float* collse = (float*)(ws + o);   o += (size_t)N * 4;
  o = (o + 255) & ~(size_t)255;
  unsigned long long* mbits = (unsigned long long*)(ws + o); o += (size_t)N * 8;
  o = (o + 255) & ~(size_t)255;
  float* candx = (float*)(ws + o);    o += (size_t)RR * CAP * 4;
  int* candn = (int*)(ws + o);        o += (size_t)RR * CAP * 4;
  int* seln = (int*)(ws + o);         o += (size_t)RR * NO * 4;

  hipMemsetAsync(ws + zero_off, 0, zero_bytes, stream);

  const int NB = (N + 255) / 256;

  k_mask<<<NB, 256, 0, stream>>>(mask, mbits, N);
  k_hsw<<<RR, 256, 0, stream>>>(hs, W, hsW);
  k_scores<<<NB, 256, 0, stream>>>(es, hsW, mbits, scores, colmax, colargmax, sums,
                                   rowmax_u, N);
  k_colpass<<<NB, 256, 0, stream>>>(scores, colmax, colargmax, mbits, sums, rowmax_u,
                                    collse, rowacc, cnt, candx, candn, N);
  k_rowfin<<<1, 64, 0, stream>>>(rowacc, rowmax_u, rowstats);
  k_topk<<<RR, 512, 0, stream>>>(cnt, candx, candn, sums, rowstats, (float*)d_out, seln,
                                 N, NO);
  k_expand<<<RR * NO, 64, 0, stream>>>(scores, sums, rowstats, colmax, collse, seln,
                                       (float*)d_out, N, NO);
}

// Round 4
// 659.497 us; speedup vs baseline: 2.9891x; 1.6860x over previous
//
#include <hip/hip_runtime.h>
#include <math.h>

#define RR 64
#define DD 256
#define CAP 6144

// ---------- helpers ----------

__device__ __forceinline__ void get_mu_istd(const double* sums, int N, float& fmu, float& istd) {
  double M = (double)RR * (double)N;
  double mu = sums[0] / M;
  double var = (sums[1] - sums[0] * sums[0] / M) / (M - 1.0);
  fmu = (float)mu;
  istd = (float)(1.0 / sqrt(var));
}

// ---------- K_mask: per-block dtype sniff (same 4KB window -> consistent) + pack ----------

__global__ __launch_bounds__(256) void k_mask(const void* __restrict__ maskp,
                                              unsigned long long* __restrict__ mbits,
                                              int N) {
  __shared__ int f;
  int tid = threadIdx.x;
  if (tid == 0) f = 0;
  __syncthreads();
  {
    const unsigned* mw = (const unsigned*)maskp;
    int mode = 0;
    for (int i = tid; i < 4096; i += 256) {
      unsigned v = mw[i];
      if (v == 0x3f800000u) mode = 2;
      else if (v > 1u && mode != 2) mode = 1;
    }
    if (mode) atomicMax(&f, mode);
  }
  __syncthreads();
  const int mode = f;

  int n = blockIdx.x * 256 + tid;
  if (n >= N) return;
  unsigned long long b = 0;
  if (mode == 1) {
    const unsigned char* m = (const unsigned char*)maskp;
#pragma unroll
    for (int r = 0; r < RR; ++r)
      b |= (unsigned long long)(m[(size_t)r * N + n] != 0) << r;
  } else if (mode == 2) {
    const float* m = (const float*)maskp;
#pragma unroll
    for (int r = 0; r < RR; ++r)
      b |= (unsigned long long)(m[(size_t)r * N + n] != 0.f) << r;
  } else {
    const int* m = (const int*)maskp;
#pragma unroll
    for (int r = 0; r < RR; ++r)
      b |= (unsigned long long)(m[(size_t)r * N + n] != 0) << r;
  }
  mbits[n] = b;
}

// ---------- K1: hsW = hs @ W   [64 x 256] ----------

__global__ __launch_bounds__(256) void k_hsw(const float* __restrict__ hs,
                                             const float* __restrict__ W,
                                             float* __restrict__ hsW) {
  int i = blockIdx.x;
  int j = threadIdx.x;
  float acc = 0.f;
  for (int k = 0; k < DD; ++k) acc = fmaf(hs[i * DD + k], W[k * DD + j], acc);
  hsW[i * DD + j] = acc;
}

// ---------- K2: scores GEMM ----------
// Round-9 = round-0 structure (best measured: 326us; identical global access
// pattern, identical LDS layout, identical accumulation order -> bitwise-same
// scores) + two targeted fixes:
//  (a) T14 register prefetch: next chunk's 10x float4 global loads issue right
//      after this chunk's ds_write; the vmcnt wait moves off the critical path
//      to one full compute phase later. (Round-0 had load->drain->ds_write
//      serialized between the two barriers every chunk.)
//  (b) NO hot-word atomics: per-block partial max/sums STORED to qpart/spart
//      (contention-free), reduced by tiny k_redmax/k_redsum kernels.
//      (100k atomicMax to 2 cache lines = suspected L2 serialization wall.)

__global__ __launch_bounds__(256) void k_scores(const float* __restrict__ es,
                                                const float* __restrict__ hsW,
                                                const unsigned long long* __restrict__ mbits,
                                                float* __restrict__ scores,
                                                float* __restrict__ colmax,
                                                int* __restrict__ colargmax,
                                                float* __restrict__ qpart,   // [NB][128]
                                                double* __restrict__ spart,  // [NB][2]
                                                int N) {
  __shared__ float lds[256 * 36];   // es tile [col][36]; reused as stat buffer
  __shared__ float wlds[64 * 32];   // hsW chunk [row][32]
  __shared__ double red[8];
  const int tid = threadIdx.x;
  const int lane = tid & 63;
  const int ty = __builtin_amdgcn_readfirstlane(tid >> 6);
  const int n0 = blockIdx.x * 256;
  const int R0 = ty * 16;
  const int nb = n0 + lane;    // col c -> nb + 64*c

  // per-thread staging coordinates (identical to round-0 stage addressing)
  const int ec = tid >> 3;          // col base within p-group
  const int ek = (tid & 7) * 4;     // k offset
  const int wrow = tid >> 2;
  const int wk = (tid & 3) * 8;

  float4 acc[16];
#pragma unroll
  for (int i = 0; i < 16; ++i) acc[i] = make_float4(0.f, 0.f, 0.f, 0.f);

  // prologue: prefetch chunk 0 into registers
  float4 er[8], wr0, wr1;
#pragma unroll
  for (int p = 0; p < 8; ++p) {
    int c = p * 32 + ec;
    int rr = min(n0 + c, N - 1);
    er[p] = *(const float4*)(es + (size_t)rr * DD + ek);
  }
  wr0 = *(const float4*)(hsW + wrow * DD + wk);
  wr1 = *(const float4*)(hsW + wrow * DD + wk + 4);

  for (int kc = 0; kc < DD; kc += 32) {
    __syncthreads();   // prev-iteration LDS readers done
    // commit prefetched regs -> LDS (no vmcnt on critical path: loads issued
    // one full compute phase ago)
#pragma unroll
    for (int p = 0; p < 8; ++p) {
      int c = p * 32 + ec;
      *(float4*)(lds + c * 36 + ek) = er[p];
    }
    *(float4*)(wlds + wrow * 32 + wk) = wr0;
    *(float4*)(wlds + wrow * 32 + wk + 4) = wr1;
    // issue next chunk's loads; they stay in flight across the barrier and
    // the whole compute phase below
    if (kc + 32 < DD) {
#pragma unroll
      for (int p = 0; p < 8; ++p) {
        int c = p * 32 + ec;
        int rr = min(n0 + c, N - 1);
        er[p] = *(const float4*)(es + (size_t)rr * DD + kc + 32 + ek);
      }
      wr0 = *(const float4*)(hsW + wrow * DD + kc + 32 + wk);
      wr1 = *(const float4*)(hsW + wrow * DD + kc + 32 + wk + 4);
    }
    __syncthreads();   // publish LDS
#pragma unroll
    for (int k = 0; k < 32; k += 4) {
      const float4 e0 = *(const float4*)(lds + (lane +   0) * 36 + k);
      const float4 e1 = *(const float4*)(lds + (lane +  64) * 36 + k);
      const float4 e2 = *(const float4*)(lds + (lane + 128) * 36 + k);
      const float4 e3 = *(const float4*)(lds + (lane + 192) * 36 + k);
#pragma unroll
      for (int i = 0; i < 16; ++i) {
        const float4 w = *(const float4*)(wlds + (R0 + i) * 32 + k);  // uniform -> broadcast
        acc[i].x = fmaf(w.x, e0.x, fmaf(w.y, e0.y, fmaf(w.z, e0.z, fmaf(w.w, e0.w, acc[i].x))));
        acc[i].y = fmaf(w.x, e1.x, fmaf(w.y, e1.y, fmaf(w.z, e1.z, fmaf(w.w, e1.w, acc[i].y))));
        acc[i].z = fmaf(w.x, e2.x, fmaf(w.y, e2.y, fmaf(w.z, e2.z, fmaf(w.w, e2.w, acc[i].z))));
        acc[i].w = fmaf(w.x, e3.x, fmaf(w.y, e3.y, fmaf(w.z, e3.z, fmaf(w.w, e3.w, acc[i].w))));
      }
    }
  }

  // ---- col validity ----
  bool val[4];
#pragma unroll
  for (int c = 0; c < 4; ++c) val[c] = (nb + 64 * c) < N;

  // ---- store scores ----
#pragma unroll
  for (int i = 0; i < 16; ++i) {
    float* dst = scores + (size_t)(R0 + i) * N + nb;
    float v[4] = {acc[i].x, acc[i].y, acc[i].z, acc[i].w};
#pragma unroll
    for (int c = 0; c < 4; ++c)
      if (val[c]) dst[64 * c] = v[c];
  }

  // ---- mask bits for my 4 cols ----
  unsigned long long mb[4];
#pragma unroll
  for (int c = 0; c < 4; ++c) mb[c] = val[c] ? mbits[nb + 64 * c] : 0ull;

  // ---- per-col partials over my 16 rows + fused row-max reductions ----
  // rows are partitioned across waves (wave ty owns rows R0..R0+15), so the
  // wave-reduced q/qm IS the block's row max -> store to qpart, no atomics.
  float ps1[4], ps2[4], pcm[4], pbv[4];
  int pbr[4];
#pragma unroll
  for (int c = 0; c < 4; ++c) { ps1[c] = 0.f; ps2[c] = 0.f; pcm[c] = -INFINITY; pbv[c] = -INFINITY; pbr[c] = -1; }

#pragma unroll
  for (int i = 0; i < 16; ++i) {
    const int rrow = R0 + i;
    float v[4] = {acc[i].x, acc[i].y, acc[i].z, acc[i].w};
    float q = -INFINITY, qm = -INFINITY;
#pragma unroll
    for (int c = 0; c < 4; ++c) {
      ps1[c] += v[c];
      ps2[c] = fmaf(v[c], v[c], ps2[c]);
      pcm[c] = fmaxf(pcm[c], v[c]);
      bool bit = (mb[c] >> rrow) & 1ull;
      if (bit && (v[c] > pbv[c])) { pbv[c] = v[c]; pbr[c] = rrow; }
      float qv = val[c] ? v[c] : -INFINITY;
      q = fmaxf(q, qv);
      if (bit) qm = fmaxf(qm, qv);
    }
#pragma unroll
    for (int o = 32; o > 0; o >>= 1) {
      q = fmaxf(q, __shfl_down(q, o));
      qm = fmaxf(qm, __shfl_down(qm, o));
    }
    if (lane == 0) {
      qpart[(size_t)blockIdx.x * 128 + rrow] = q;
      qpart[(size_t)blockIdx.x * 128 + 64 + rrow] = qm;
    }
  }

  // ---- cross-wave col-stat combine via LDS ----
  __syncthreads();   // done with es tile
  float* Ls1 = lds;
  float* Ls2 = lds + 1024;
  float* Lcm = lds + 2048;
  float* Lbv = lds + 3072;
  int* Lbr = (int*)(lds + 4096);
#pragma unroll
  for (int c = 0; c < 4; ++c) {
    int col = lane + 64 * c;
    Ls1[ty * 256 + col] = ps1[c];
    Ls2[ty * 256 + col] = ps2[c];
    Lcm[ty * 256 + col] = pcm[c];
    Lbv[ty * 256 + col] = pbv[c];
    Lbr[ty * 256 + col] = pbr[c];
  }
  __syncthreads();

  const int n = n0 + tid;
  float s1 = 0.f, s2 = 0.f;
  if (n < N) {
    s1 = Ls1[tid] + Ls1[256 + tid] + Ls1[512 + tid] + Ls1[768 + tid];
    s2 = Ls2[tid] + Ls2[256 + tid] + Ls2[512 + tid] + Ls2[768 + tid];
    float cm = fmaxf(fmaxf(Lcm[tid], Lcm[256 + tid]), fmaxf(Lcm[512 + tid], Lcm[768 + tid]));
    colmax[n] = cm;
    float bv = -INFINITY;
    int br = -1;
#pragma unroll
    for (int w2 = 0; w2 < 4; ++w2) {
      float b = Lbv[w2 * 256 + tid];
      if (b > bv) { bv = b; br = Lbr[w2 * 256 + tid]; }
    }
    colargmax[n] = br;
  }

  double d1 = (double)s1, d2 = (double)s2;
#pragma unroll
  for (int o = 32; o > 0; o >>= 1) {
    d1 += __shfl_down(d1, o);
    d2 += __shfl_down(d2, o);
  }
  if ((tid & 63) == 0) { red[ty * 2] = d1; red[ty * 2 + 1] = d2; }
  __syncthreads();
  if (tid == 0) {
    spart[(size_t)blockIdx.x * 2] = red[0] + red[2] + red[4] + red[6];
    spart[(size_t)blockIdx.x * 2 + 1] = red[1] + red[3] + red[5] + red[7];
  }
}

// ---------- K2b: reduce per-block row maxes (128 slots: 64 unmasked + 64 masked) ----------

__global__ __launch_bounds__(256) void k_redmax(const float* __restrict__ qpart,
                                                float* __restrict__ rowmaxf,
                                                int NBlk) {
  const int slot = blockIdx.x;   // 0..127
  const int tid = threadIdx.x, lane = tid & 63, ty = tid >> 6;
  __shared__ float w[4];
  float m = -INFINITY;
  for (int i = tid; i < NBlk; i += 256) m = fmaxf(m, qpart[(size_t)i * 128 + slot]);
#pragma unroll
  for (int o = 32; o > 0; o >>= 1) m = fmaxf(m, __shfl_down(m, o));
  if (lane == 0) w[ty] = m;
  __syncthreads();
  if (tid == 0) rowmaxf[slot] = fmaxf(fmaxf(w[0], w[1]), fmaxf(w[2], w[3]));
}

// ---------- K2c: reduce per-block sums (deterministic order) ----------

__global__ __launch_bounds__(256) void k_redsum(const double* __restrict__ spart,
                                                double* __restrict__ sums,
                                                int NBlk) {
  const int tid = threadIdx.x, lane = tid & 63, ty = tid >> 6;
  __shared__ double r[8];
  double s0 = 0.0, s1 = 0.0;
  for (int i = tid; i < NBlk; i += 256) {
    s0 += spart[(size_t)i * 2];
    s1 += spart[(size_t)i * 2 + 1];
  }
#pragma unroll
  for (int o = 32; o > 0; o >>= 1) {
    s0 += __shfl_down(s0, o);
    s1 += __shfl_down(s1, o);
  }
  if (lane == 0) { r[ty * 2] = s0; r[ty * 2 + 1] = s1; }
  __syncthreads();
  if (tid == 0) {
    sums[0] = r[0] + r[2] + r[4] + r[6];
    sums[1] = r[1] + r[3] + r[5] + r[7];
  }
}

// ---------- K4: fused column pass: collse + row exp-sums + candidate scatter ----------
// 1-expf factorization (verified round-2). Row exp-sum partials now STORED
// per block (colpart), reduced by k_redacc -- no hot-word atomicAdds.

__global__ __launch_bounds__(256) void k_colpass(const float* __restrict__ scores,
                                                 const float* __restrict__ colmax,
                                                 const int* __restrict__ colargmax,
                                                 const unsigned long long* __restrict__ mbits,
                                                 const double* __restrict__ sums,
                                                 const float* __restrict__ rowmaxf,
                                                 float* __restrict__ collse,
                                                 float* __restrict__ colpart,  // [NB][128]
                                                 int* __restrict__ cnt,
                                                 float* __restrict__ candx,
                                                 int* __restrict__ candn,
                                                 int N) {
  __shared__ float rmS[64], suS[64], smS[64];
  __shared__ float rpu[64 * 4], rpm[64 * 4];
  __shared__ int lcnt[64], lbase[64];
  const int tid = threadIdx.x, lane = tid & 63, ty = tid >> 6;
  float fmu, istd;
  get_mu_istd(sums, N, fmu, istd);
  if (tid < 64) {
    rmS[tid] = rowmaxf[tid];
    lcnt[tid] = 0;
  }
  __syncthreads();
  // every thread computes gm (uniform LDS broadcasts, cheap)
  float gm = rmS[0];
#pragma unroll
  for (int r = 1; r < RR; ++r) gm = fmaxf(gm, rmS[r]);
  if (tid < 64) {
    suS[tid] = expf((gm - rmS[tid]) * istd);
    smS[tid] = expf((gm - rowmaxf[64 + tid]) * istd);
  }
  // suS/smS consumed only after the later __syncthreads()

  const int n = blockIdx.x * 256 + tid;
  const bool valid = n < N;
  const float cm = valid ? colmax[n] : 0.f;
  const int br = valid ? colargmax[n] : -1;
  const unsigned long long mbn = valid ? mbits[n] : 0ull;
  float colsum = 0.f, xbr = 0.f;

  for (int r = 0; r < RR; ++r) {
    float x = valid ? scores[(size_t)r * N + n] : 0.f;
    if (r == br) xbr = x;
    float E = valid ? expf((x - gm) * istd) : 0.f;
    colsum += E;
    float eu = E;
    float em = ((mbn >> r) & 1ull) ? E : 0.f;
#pragma unroll
    for (int o = 32; o > 0; o >>= 1) {
      eu += __shfl_down(eu, o);
      em += __shfl_down(em, o);
    }
    if (lane == 0) { rpu[r * 4 + ty] = eu; rpm[r * 4 + ty] = em; }
  }

  if (valid) collse[n] = logf(colsum) + (gm - cm) * istd;
  int lpos = 0;
  if (br >= 0) lpos = atomicAdd(&lcnt[br], 1);
  __syncthreads();
  if (tid < 64) {
    float su = (rpu[tid * 4] + rpu[tid * 4 + 1] + rpu[tid * 4 + 2] + rpu[tid * 4 + 3]) * suS[tid];
    float sm = (rpm[tid * 4] + rpm[tid * 4 + 1] + rpm[tid * 4 + 2] + rpm[tid * 4 + 3]) * smS[tid];
    colpart[(size_t)blockIdx.x * 128 + tid] = su;
    colpart[(size_t)blockIdx.x * 128 + 64 + tid] = sm;
    int c = lcnt[tid];
    lbase[tid] = c ? atomicAdd(&cnt[tid], c) : 0;
  }
  __syncthreads();
  if (br >= 0) {
    int pos = lbase[br] + lpos;
    if (pos < CAP) {
      candx[(size_t)br * CAP + pos] = xbr;
      candn[(size_t)br * CAP + pos] = n;
    }
  }
}

// ---------- K4b: reduce row exp-sum partials + finalize row stats ----------

__global__ __launch_bounds__(256) void k_redacc(const float* __restrict__ colpart,
                                                const float* __restrict__ rowmaxf,
                                                float* __restrict__ rowstats,
                                                int NBlk) {
  const int slot = blockIdx.x;   // 0..127
  const int tid = threadIdx.x, lane = tid & 63, ty = tid >> 6;
  __shared__ float w[4];
  float s = 0.f;
  for (int i = tid; i < NBlk; i += 256) s += colpart[(size_t)i * 128 + slot];
#pragma unroll
  for (int o = 32; o > 0; o >>= 1) s += __shfl_down(s, o);
  if (lane == 0) w[ty] = s;
  __syncthreads();
  if (tid == 0) {
    float total = w[0] + w[1] + w[2] + w[3];
    if (slot < 64) {
      rowstats[slot] = rowmaxf[slot];
      rowstats[64 + slot] = logf(total);
    } else {
      rowstats[128 + (slot - 64)] = rowmaxf[slot];
      rowstats[192 + (slot - 64)] = total;
    }
  }
}

// ---------- K5: per-row top-50 (prob desc, index asc), 512 threads ----------

__global__ __launch_bounds__(512) void k_topk(const int* __restrict__ cnt,
                                              const float* __restrict__ candx,
                                              const int* __restrict__ candn,
                                              const double* __restrict__ sums,
                                              const float* __restrict__ rowstats,
                                              float* __restrict__ out,
                                              int* __restrict__ seln,
                                              int N, int NO) {
  int r = blockIdx.x, tid = threadIdx.x;
  __shared__ float sp[CAP];
  __shared__ int sn[CAP];
  __shared__ float wp[8];
  __shared__ int wn[8], wi[8];
  int c = min(cnt[r], CAP);
  float fmu, istd;
  get_mu_istd(sums, N, fmu, istd);
  const float rmm = rowstats[128 + r];
  const float lm = rowstats[192 + r];
  for (int i = tid; i < c; i += 512) {
    float xv = candx[(size_t)r * CAP + i];
    sp[i] = fmaxf(expf((xv - rmm) * istd) / lm, 1e-6f);
    sn[i] = candn[(size_t)r * CAP + i];
  }
  __syncthreads();
  for (int j = 0; j < NO; ++j) {
    float bp = -1.f;
    int bn = 0x7fffffff, bi = -1;
    for (int i = tid; i < c; i += 512) {
      float p = sp[i];
      int nn = sn[i];
      if (p > bp || (p == bp && nn < bn)) { bp = p; bn = nn; bi = i; }
    }
#pragma unroll
    for (int o = 32; o > 0; o >>= 1) {
      float p2 = __shfl_down(bp, o);
      int n2 = __shfl_down(bn, o);
      int i2 = __shfl_down(bi, o);
      if (p2 > bp || (p2 == bp && n2 < bn)) { bp = p2; bn = n2; bi = i2; }
    }
    if ((tid & 63) == 0) { wp[tid >> 6] = bp; wn[tid >> 6] = bn; wi[tid >> 6] = bi; }
    __syncthreads();
    if (tid == 0) {
      float fp2 = wp[0]; int fn2 = wn[0], fi2 = wi[0];
#pragma unroll
      for (int w2 = 1; w2 < 8; ++w2) {
        if (wp[w2] > fp2 || (wp[w2] == fp2 && wn[w2] < fn2)) { fp2 = wp[w2]; fn2 = wn[w2]; fi2 = wi[w2]; }
      }
      if (fp2 > 0.f) {
        out[r * NO + j] = (float)fn2;
        seln[r * NO + j] = fn2;
        sp[fi2] = -1.f;
      } else {
        out[r * NO + j] = -1.f;
        seln[r * NO + j] = -1;
      }
    }
    __syncthreads();
  }
}

// ---------- K6: exp_scores ----------

__global__ void k_expand(const float* __restrict__ scores,
                         const double* __restrict__ sums,
                         const float* __restrict__ rowstats,
                         const float* __restrict__ colmax,
                         const float* __restrict__ collse,
                         const int* __restrict__ seln,
                         float* __restrict__ out,
                         int N, int NO) {
  int b = blockIdx.x;
  int r2 = threadIdx.x;
  int n = seln[b];
  float v = 0.f;
  if (n >= 0) {
    float fmu, istd;
    get_mu_istd(sums, N, fmu, istd);
    float x = scores[(size_t)r2 * N + n];
    float v1 = (x - rowstats[r2]) * istd - rowstats[64 + r2];
    float v2 = (x - colmax[n]) * istd - collse[n];
    v = v1 + v2;
  }
  out[RR * NO + (size_t)b * RR + r2] = v;
}

// ---------- launch ----------

extern "C" void kernel_launch(void* const* d_in, const int* in_sizes, int n_in,
                              void* d_out, int out_size, void* d_ws, size_t ws_size,
                              hipStream_t stream) {
  const float* hs = (const float*)d_in[0];
  const float* es = (const float*)d_in[1];
  const float* W = (const float*)d_in[2];
  const void* mask = d_in[3];

  const int N = in_sizes[1] / DD;               // 200000
  const int NO = out_size / (RR * (1 + RR));    // 50
  const int NB = (N + 255) / 256;

  char* ws = (char*)d_ws;
  size_t o = 0;
  float* scores = (float*)(ws + o);   o += (size_t)RR * N * 4;
  float* hsW = (float*)(ws + o);      o += RR * DD * 4;
  o = (o + 255) & ~(size_t)255;
  // zero region: sums(16) + cnt(256)
  double* sums = (double*)(ws + o);
  int* cnt = (int*)(ws + o + 16);
  size_t zero_off = o, zero_bytes = 16 + 256;
  o += 512;
  float* rowstats = (float*)(ws + o); o += 256 * 4;
  float* rowmaxf = (float*)(ws + o);  o += 128 * 4;
  o = (o + 255) & ~(size_t)255;
  float* colmax = (float*)(ws + o);   o += (size_t)N * 4;
  int* colargmax = (int*)(ws + o);    o += (size_t)N * 4;
  float* collse = (float*)(ws + o);   o += (size_t)N * 4;
  o = (o + 255) & ~(size_t)255;
  unsigned long long* mbits = (unsigned long long*)(ws + o); o += (size_t)N * 8;
  o = (o + 255) & ~(size_t)255;
  float* candx = (float*)(ws + o);    o += (size_t)RR * CAP * 4;
  int* candn = (int*)(ws + o);        o += (size_t)RR * CAP * 4;
  int* seln = (int*)(ws + o);         o += (size_t)RR * NO * 4;
  o = (o + 255) & ~(size_t)255;
  float* qpart = (float*)(ws + o);    o += (size_t)NB * 128 * 4;
  double* spart = (double*)(ws + o);  o += (size_t)NB * 2 * 8;
  float* colpart = (float*)(ws + o);  o += (size_t)NB * 128 * 4;

  hipMemsetAsync(ws + zero_off, 0, zero_bytes, stream);

  k_mask<<<NB, 256, 0, stream>>>(mask, mbits, N);
  k_hsw<<<RR, 256, 0, stream>>>(hs, W, hsW);
  k_scores<<<NB, 256, 0, stream>>>(es, hsW, mbits, scores, colmax, colargmax,
                                   qpart, spart, N);
  k_redmax<<<128, 256, 0, stream>>>(qpart, rowmaxf, NB);
  k_redsum<<<1, 256, 0, stream>>>(spart, sums, NB);
  k_colpass<<<NB, 256, 0, stream>>>(scores, colmax, colargmax, mbits, sums, rowmaxf,
                                    collse, colpart, cnt, candx, candn, N);
  k_redacc<<<128, 256, 0, stream>>>(colpart, rowmaxf, rowstats, NB);
  k_topk<<<RR, 512, 0, stream>>>(cnt, candx, candn, sums, rowstats, (float*)d_out, seln,
                                 N, NO);
  k_expand<<<RR * NO, 64, 0, stream>>>(scores, sums, rowstats, colmax, collse, seln,
                                       (float*)d_out, N, NO);
}

// Round 5
// 632.698 us; speedup vs baseline: 3.1157x; 1.0424x over previous
//
#include <hip/hip_runtime.h>
#include <math.h>

#define RR 64
#define DD 256
#define CAP 6144

// ---------- helpers ----------

__device__ __forceinline__ void get_mu_istd(const double* sums, int N, float& fmu, float& istd) {
  double M = (double)RR * (double)N;
  double mu = sums[0] / M;
  double var = (sums[1] - sums[0] * sums[0] / M) / (M - 1.0);
  fmu = (float)mu;
  istd = (float)(1.0 / sqrt(var));
}

// async global->LDS, 16B per lane. LDS dest = wave-uniform base + lane*16.
__device__ __forceinline__ void cp16(const void* g, void* l) {
  __builtin_amdgcn_global_load_lds((const __attribute__((address_space(1))) void*)g,
                                   (__attribute__((address_space(3))) void*)l, 16, 0, 0);
}

// ---------- K_mask: per-block dtype sniff (same 4KB window -> consistent) + pack ----------

__global__ __launch_bounds__(256) void k_mask(const void* __restrict__ maskp,
                                              unsigned long long* __restrict__ mbits,
                                              int N) {
  __shared__ int f;
  int tid = threadIdx.x;
  if (tid == 0) f = 0;
  __syncthreads();
  {
    const unsigned* mw = (const unsigned*)maskp;
    int mode = 0;
    for (int i = tid; i < 4096; i += 256) {
      unsigned v = mw[i];
      if (v == 0x3f800000u) mode = 2;
      else if (v > 1u && mode != 2) mode = 1;
    }
    if (mode) atomicMax(&f, mode);
  }
  __syncthreads();
  const int mode = f;

  int n = blockIdx.x * 256 + tid;
  if (n >= N) return;
  unsigned long long b = 0;
  if (mode == 1) {
    const unsigned char* m = (const unsigned char*)maskp;
#pragma unroll
    for (int r = 0; r < RR; ++r)
      b |= (unsigned long long)(m[(size_t)r * N + n] != 0) << r;
  } else if (mode == 2) {
    const float* m = (const float*)maskp;
#pragma unroll
    for (int r = 0; r < RR; ++r)
      b |= (unsigned long long)(m[(size_t)r * N + n] != 0.f) << r;
  } else {
    const int* m = (const int*)maskp;
#pragma unroll
    for (int r = 0; r < RR; ++r)
      b |= (unsigned long long)(m[(size_t)r * N + n] != 0) << r;
  }
  mbits[n] = b;
}

// ---------- K1: hsW = hs @ W   [64 x 256] ----------

__global__ __launch_bounds__(256) void k_hsw(const float* __restrict__ hs,
                                             const float* __restrict__ W,
                                             float* __restrict__ hsW) {
  int i = blockIdx.x;
  int j = threadIdx.x;
  float acc = 0.f;
  for (int k = 0; k < DD; ++k) acc = fmaf(hs[i * DD + k], W[k * DD + j], acc);
  hsW[i * DD + j] = acc;
}

// ---------- K2: scores GEMM ----------
// Round-10: round-4's pipeline schedule, but the prefetch moved from VGPRs
// (which spilled: VGPR=112 cap, WRITE_SIZE 190MB of scratch evictions) into
// global_load_lds double-buffering:
//  - es tile: UNPADDED [col][32] dwords, dbuf. cp16's linear dest (base +
//    lane*16B) reproduces round-0's staging geometry exactly: per wave-inst
//    8 consecutive rows x full 128B row-segment, granules permuted WITHIN
//    each 128B line (g = (lane&7)^((lane>>3)&7)) -> line-granularity traffic
//    identical to round 0 (round-1's blowup was its 64B-granule scatter).
//  - read side applies the same XOR (slot = (k>>2)^(col&7)): rule #21
//    both-sides swizzle -> 2 lanes/bank-quad per quarter-wave = free.
//  - hsW: [k-half][row][16] layout via 2 cp16/thread; reads stay uniform
//    broadcasts.
//  - zero prefetch VGPRs -> no spill. LDS 80KB -> 2 blocks/CU; prefetch
//    issued before a ~4096-cycle FMA phase, vmcnt(0) only at chunk boundary.
// FMA nesting and k-order identical to rounds 0/4 -> bitwise-same scores.

__global__ __launch_bounds__(256) void k_scores(const float* __restrict__ es,
                                                const float* __restrict__ hsW,
                                                const unsigned long long* __restrict__ mbits,
                                                float* __restrict__ scores,
                                                float* __restrict__ colmax,
                                                int* __restrict__ colargmax,
                                                float* __restrict__ qpart,   // [NB][128]
                                                double* __restrict__ spart,  // [NB][2]
                                                int N) {
  // LDS dwords: [0,16384) es dbuf (8192 each: 256 cols x 32 dw, granule-XOR)
  //             [16384,20480) w dbuf (2048 each: (k>>4)*1024 + row*16 + (k&15))
  // stats phase reuses [0,5136) after the final barrier.
  __shared__ float lds[20480];   // 80 KB exactly -> 2 blocks/CU
  const int tid = threadIdx.x;
  const int lane = tid & 63;
  const int ty = __builtin_amdgcn_readfirstlane(tid >> 6);
  const int n0 = blockIdx.x * 256;
  const int R0 = ty * 16;
  const int nb = n0 + lane;    // col c -> nb + 64*c

  // staging coords (per thread, loop-invariant)
  const int srow = ty * 8 + (lane >> 3);                 // col = p*32 + srow
  const int sg4 = (((lane & 7) ^ ((lane >> 3) & 7)) << 2);  // pre-swizzled src granule (dwords)
  const int wrow = ty * 16 + (lane >> 2);
  const int wg4 = (lane & 3) << 2;

  float4 acc[16];
#pragma unroll
  for (int i = 0; i < 16; ++i) acc[i] = make_float4(0.f, 0.f, 0.f, 0.f);

  auto stage = [&](float* ebase, float* wbase, int kc) {
#pragma unroll
    for (int p = 0; p < 8; ++p) {
      const int col = p * 32 + srow;
      const int rr = min(n0 + col, N - 1);
      cp16(es + (size_t)rr * DD + kc + sg4, ebase + p * 1024 + ty * 256);
    }
    cp16(hsW + (size_t)wrow * DD + kc + wg4, wbase + ty * 256);
    cp16(hsW + (size_t)wrow * DD + kc + 16 + wg4, wbase + 1024 + ty * 256);
  };

  // prologue: stage chunk 0 into buf0
  stage(lds, lds + 16384, 0);
  asm volatile("s_waitcnt vmcnt(0)" ::: "memory");
  __syncthreads();

  const int swz = (lane & 7);   // read-side XOR term

  for (int kc = 0; kc < DD; kc += 32) {
    const int cur = (kc >> 5) & 1;
    float* ebC = lds + (cur ? 8192 : 0);
    float* wbC = lds + 16384 + (cur ? 2048 : 0);
    if (kc + 32 < DD) {
      float* ebN = lds + (cur ? 0 : 8192);
      float* wbN = lds + 16384 + (cur ? 0 : 2048);
      stage(ebN, wbN, kc + 32);   // async; drains at loop-end barrier
    }
#pragma unroll
    for (int k = 0; k < 32; k += 4) {
      const int eswz = (((k >> 2) ^ swz) << 2);
      const float4 e0 = *(const float4*)(ebC + (lane       ) * 32 + eswz);
      const float4 e1 = *(const float4*)(ebC + (lane +  64 ) * 32 + eswz);
      const float4 e2 = *(const float4*)(ebC + (lane + 128 ) * 32 + eswz);
      const float4 e3 = *(const float4*)(ebC + (lane + 192 ) * 32 + eswz);
      const float* wk = wbC + ((k >> 4) * 1024) + (k & 15);
#pragma unroll
      for (int i = 0; i < 16; ++i) {
        const float4 w = *(const float4*)(wk + (R0 + i) * 16);  // uniform -> broadcast
        acc[i].x = fmaf(w.x, e0.x, fmaf(w.y, e0.y, fmaf(w.z, e0.z, fmaf(w.w, e0.w, acc[i].x))));
        acc[i].y = fmaf(w.x, e1.x, fmaf(w.y, e1.y, fmaf(w.z, e1.z, fmaf(w.w, e1.w, acc[i].y))));
        acc[i].z = fmaf(w.x, e2.x, fmaf(w.y, e2.y, fmaf(w.z, e2.z, fmaf(w.w, e2.w, acc[i].z))));
        acc[i].w = fmaf(w.x, e3.x, fmaf(w.y, e3.y, fmaf(w.z, e3.z, fmaf(w.w, e3.w, acc[i].w))));
      }
    }
    // drain prefetch + protect buffer swap (one barrier per chunk)
    asm volatile("s_waitcnt vmcnt(0)" ::: "memory");
    __syncthreads();
  }

  // ---- col validity ----
  bool val[4];
#pragma unroll
  for (int c = 0; c < 4; ++c) val[c] = (nb + 64 * c) < N;

  // ---- store scores ----
#pragma unroll
  for (int i = 0; i < 16; ++i) {
    float* dst = scores + (size_t)(R0 + i) * N + nb;
    float v[4] = {acc[i].x, acc[i].y, acc[i].z, acc[i].w};
#pragma unroll
    for (int c = 0; c < 4; ++c)
      if (val[c]) dst[64 * c] = v[c];
  }

  // ---- mask bits for my 4 cols ----
  unsigned long long mb[4];
#pragma unroll
  for (int c = 0; c < 4; ++c) mb[c] = val[c] ? mbits[nb + 64 * c] : 0ull;

  // ---- per-col partials over my 16 rows + fused row-max reductions ----
  float ps1[4], ps2[4], pcm[4], pbv[4];
  int pbr[4];
#pragma unroll
  for (int c = 0; c < 4; ++c) { ps1[c] = 0.f; ps2[c] = 0.f; pcm[c] = -INFINITY; pbv[c] = -INFINITY; pbr[c] = -1; }

#pragma unroll
  for (int i = 0; i < 16; ++i) {
    const int rrow = R0 + i;
    float v[4] = {acc[i].x, acc[i].y, acc[i].z, acc[i].w};
    float q = -INFINITY, qm = -INFINITY;
#pragma unroll
    for (int c = 0; c < 4; ++c) {
      ps1[c] += v[c];
      ps2[c] = fmaf(v[c], v[c], ps2[c]);
      pcm[c] = fmaxf(pcm[c], v[c]);
      bool bit = (mb[c] >> rrow) & 1ull;
      if (bit && (v[c] > pbv[c])) { pbv[c] = v[c]; pbr[c] = rrow; }
      float qv = val[c] ? v[c] : -INFINITY;
      q = fmaxf(q, qv);
      if (bit) qm = fmaxf(qm, qv);
    }
#pragma unroll
    for (int o = 32; o > 0; o >>= 1) {
      q = fmaxf(q, __shfl_down(q, o));
      qm = fmaxf(qm, __shfl_down(qm, o));
    }
    if (lane == 0) {
      qpart[(size_t)blockIdx.x * 128 + rrow] = q;
      qpart[(size_t)blockIdx.x * 128 + 64 + rrow] = qm;
    }
  }

  // ---- cross-wave col-stat combine via LDS (reuse es buf0) ----
  __syncthreads();   // all waves past final loop barrier; es bufs dead
  float* Ls1 = lds;
  float* Ls2 = lds + 1024;
  float* Lcm = lds + 2048;
  float* Lbv = lds + 3072;
  int* Lbr = (int*)(lds + 4096);
  double* red = (double*)(lds + 5120);
#pragma unroll
  for (int c = 0; c < 4; ++c) {
    int col = lane + 64 * c;
    Ls1[ty * 256 + col] = ps1[c];
    Ls2[ty * 256 + col] = ps2[c];
    Lcm[ty * 256 + col] = pcm[c];
    Lbv[ty * 256 + col] = pbv[c];
    Lbr[ty * 256 + col] = pbr[c];
  }
  __syncthreads();

  const int n = n0 + tid;
  float s1 = 0.f, s2 = 0.f;
  if (n < N) {
    s1 = Ls1[tid] + Ls1[256 + tid] + Ls1[512 + tid] + Ls1[768 + tid];
    s2 = Ls2[tid] + Ls2[256 + tid] + Ls2[512 + tid] + Ls2[768 + tid];
    float cm = fmaxf(fmaxf(Lcm[tid], Lcm[256 + tid]), fmaxf(Lcm[512 + tid], Lcm[768 + tid]));
    colmax[n] = cm;
    float bv = -INFINITY;
    int br = -1;
#pragma unroll
    for (int w2 = 0; w2 < 4; ++w2) {
      float b = Lbv[w2 * 256 + tid];
      if (b > bv) { bv = b; br = Lbr[w2 * 256 + tid]; }
    }
    colargmax[n] = br;
  }

  double d1 = (double)s1, d2 = (double)s2;
#pragma unroll
  for (int o = 32; o > 0; o >>= 1) {
    d1 += __shfl_down(d1, o);
    d2 += __shfl_down(d2, o);
  }
  if ((tid & 63) == 0) { red[ty * 2] = d1; red[ty * 2 + 1] = d2; }
  __syncthreads();
  if (tid == 0) {
    spart[(size_t)blockIdx.x * 2] = red[0] + red[2] + red[4] + red[6];
    spart[(size_t)blockIdx.x * 2 + 1] = red[1] + red[3] + red[5] + red[7];
  }
}

// ---------- K2b: reduce per-block row maxes (128 slots: 64 unmasked + 64 masked) ----------

__global__ __launch_bounds__(256) void k_redmax(const float* __restrict__ qpart,
                                                float* __restrict__ rowmaxf,
                                                int NBlk) {
  const int slot = blockIdx.x;   // 0..127
  const int tid = threadIdx.x, lane = tid & 63, ty = tid >> 6;
  __shared__ float w[4];
  float m = -INFINITY;
  for (int i = tid; i < NBlk; i += 256) m = fmaxf(m, qpart[(size_t)i * 128 + slot]);
#pragma unroll
  for (int o = 32; o > 0; o >>= 1) m = fmaxf(m, __shfl_down(m, o));
  if (lane == 0) w[ty] = m;
  __syncthreads();
  if (tid == 0) rowmaxf[slot] = fmaxf(fmaxf(w[0], w[1]), fmaxf(w[2], w[3]));
}

// ---------- K2c: reduce per-block sums (deterministic order) ----------

__global__ __launch_bounds__(256) void k_redsum(const double* __restrict__ spart,
                                                double* __restrict__ sums,
                                                int NBlk) {
  const int tid = threadIdx.x, lane = tid & 63, ty = tid >> 6;
  __shared__ double r[8];
  double s0 = 0.0, s1 = 0.0;
  for (int i = tid; i < NBlk; i += 256) {
    s0 += spart[(size_t)i * 2];
    s1 += spart[(size_t)i * 2 + 1];
  }
#pragma unroll
  for (int o = 32; o > 0; o >>= 1) {
    s0 += __shfl_down(s0, o);
    s1 += __shfl_down(s1, o);
  }
  if (lane == 0) { r[ty * 2] = s0; r[ty * 2 + 1] = s1; }
  __syncthreads();
  if (tid == 0) {
    sums[0] = r[0] + r[2] + r[4] + r[6];
    sums[1] = r[1] + r[3] + r[5] + r[7];
  }
}

// ---------- K4: fused column pass: collse + row exp-sums + candidate scatter ----------
// 1-expf factorization (verified round-2). Row exp-sum partials STORED per
// block (colpart), reduced by k_redacc -- no hot-word atomicAdds.

__global__ __launch_bounds__(256) void k_colpass(const float* __restrict__ scores,
                                                 const float* __restrict__ colmax,
                                                 const int* __restrict__ colargmax,
                                                 const unsigned long long* __restrict__ mbits,
                                                 const double* __restrict__ sums,
                                                 const float* __restrict__ rowmaxf,
                                                 float* __restrict__ collse,
                                                 float* __restrict__ colpart,  // [NB][128]
                                                 int* __restrict__ cnt,
                                                 float* __restrict__ candx,
                                                 int* __restrict__ candn,
                                                 int N) {
  __shared__ float rmS[64], suS[64], smS[64];
  __shared__ float rpu[64 * 4], rpm[64 * 4];
  __shared__ int lcnt[64], lbase[64];
  const int tid = threadIdx.x, lane = tid & 63, ty = tid >> 6;
  float fmu, istd;
  get_mu_istd(sums, N, fmu, istd);
  if (tid < 64) {
    rmS[tid] = rowmaxf[tid];
    lcnt[tid] = 0;
  }
  __syncthreads();
  // every thread computes gm (uniform LDS broadcasts, cheap)
  float gm = rmS[0];
#pragma unroll
  for (int r = 1; r < RR; ++r) gm = fmaxf(gm, rmS[r]);
  if (tid < 64) {
    suS[tid] = expf((gm - rmS[tid]) * istd);
    smS[tid] = expf((gm - rowmaxf[64 + tid]) * istd);
  }
  // suS/smS consumed only after the later __syncthreads()

  const int n = blockIdx.x * 256 + tid;
  const bool valid = n < N;
  const float cm = valid ? colmax[n] : 0.f;
  const int br = valid ? colargmax[n] : -1;
  const unsigned long long mbn = valid ? mbits[n] : 0ull;
  float colsum = 0.f, xbr = 0.f;

  for (int r = 0; r < RR; ++r) {
    float x = valid ? scores[(size_t)r * N + n] : 0.f;
    if (r == br) xbr = x;
    float E = valid ? expf((x - gm) * istd) : 0.f;
    colsum += E;
    float eu = E;
    float em = ((mbn >> r) & 1ull) ? E : 0.f;
#pragma unroll
    for (int o = 32; o > 0; o >>= 1) {
      eu += __shfl_down(eu, o);
      em += __shfl_down(em, o);
    }
    if (lane == 0) { rpu[r * 4 + ty] = eu; rpm[r * 4 + ty] = em; }
  }

  if (valid) collse[n] = logf(colsum) + (gm - cm) * istd;
  int lpos = 0;
  if (br >= 0) lpos = atomicAdd(&lcnt[br], 1);
  __syncthreads();
  if (tid < 64) {
    float su = (rpu[tid * 4] + rpu[tid * 4 + 1] + rpu[tid * 4 + 2] + rpu[tid * 4 + 3]) * suS[tid];
    float sm = (rpm[tid * 4] + rpm[tid * 4 + 1] + rpm[tid * 4 + 2] + rpm[tid * 4 + 3]) * smS[tid];
    colpart[(size_t)blockIdx.x * 128 + tid] = su;
    colpart[(size_t)blockIdx.x * 128 + 64 + tid] = sm;
    int c = lcnt[tid];
    lbase[tid] = c ? atomicAdd(&cnt[tid], c) : 0;
  }
  __syncthreads();
  if (br >= 0) {
    int pos = lbase[br] + lpos;
    if (pos < CAP) {
      candx[(size_t)br * CAP + pos] = xbr;
      candn[(size_t)br * CAP + pos] = n;
    }
  }
}

// ---------- K4b: reduce row exp-sum partials + finalize row stats ----------

__global__ __launch_bounds__(256) void k_redacc(const float* __restrict__ colpart,
                                                const float* __restrict__ rowmaxf,
                                                float* __restrict__ rowstats,
                                                int NBlk) {
  const int slot = blockIdx.x;   // 0..127
  const int tid = threadIdx.x, lane = tid & 63, ty = tid >> 6;
  __shared__ float w[4];
  float s = 0.f;
  for (int i = tid; i < NBlk; i += 256) s += colpart[(size_t)i * 128 + slot];
#pragma unroll
  for (int o = 32; o > 0; o >>= 1) s += __shfl_down(s, o);
  if (lane == 0) w[ty] = s;
  __syncthreads();
  if (tid == 0) {
    float total = w[0] + w[1] + w[2] + w[3];
    if (slot < 64) {
      rowstats[slot] = rowmaxf[slot];
      rowstats[64 + slot] = logf(total);
    } else {
      rowstats[128 + (slot - 64)] = rowmaxf[slot];
      rowstats[192 + (slot - 64)] = total;
    }
  }
}

// ---------- K5: per-row top-50 (prob desc, index asc), 512 threads ----------

__global__ __launch_bounds__(512) void k_topk(const int* __restrict__ cnt,
                                              const float* __restrict__ candx,
                                              const int* __restrict__ candn,
                                              const double* __restrict__ sums,
                                              const float* __restrict__ rowstats,
                                              float* __restrict__ out,
                                              int* __restrict__ seln,
                                              int N, int NO) {
  int r = blockIdx.x, tid = threadIdx.x;
  __shared__ float sp[CAP];
  __shared__ int sn[CAP];
  __shared__ float wp[8];
  __shared__ int wn[8], wi[8];
  int c = min(cnt[r], CAP);
  float fmu, istd;
  get_mu_istd(sums, N, fmu, istd);
  const float rmm = rowstats[128 + r];
  const float lm = rowstats[192 + r];
  for (int i = tid; i < c; i += 512) {
    float xv = candx[(size_t)r * CAP + i];
    sp[i] = fmaxf(expf((xv - rmm) * istd) / lm, 1e-6f);
    sn[i] = candn[(size_t)r * CAP + i];
  }
  __syncthreads();
  for (int j = 0; j < NO; ++j) {
    float bp = -1.f;
    int bn = 0x7fffffff, bi = -1;
    for (int i = tid; i < c; i += 512) {
      float p = sp[i];
      int nn = sn[i];
      if (p > bp || (p == bp && nn < bn)) { bp = p; bn = nn; bi = i; }
    }
#pragma unroll
    for (int o = 32; o > 0; o >>= 1) {
      float p2 = __shfl_down(bp, o);
      int n2 = __shfl_down(bn, o);
      int i2 = __shfl_down(bi, o);
      if (p2 > bp || (p2 == bp && n2 < bn)) { bp = p2; bn = n2; bi = i2; }
    }
    if ((tid & 63) == 0) { wp[tid >> 6] = bp; wn[tid >> 6] = bn; wi[tid >> 6] = bi; }
    __syncthreads();
    if (tid == 0) {
      float fp2 = wp[0]; int fn2 = wn[0], fi2 = wi[0];
#pragma unroll
      for (int w2 = 1; w2 < 8; ++w2) {
        if (wp[w2] > fp2 || (wp[w2] == fp2 && wn[w2] < fn2)) { fp2 = wp[w2]; fn2 = wn[w2]; fi2 = wi[w2]; }
      }
      if (fp2 > 0.f) {
        out[r * NO + j] = (float)fn2;
        seln[r * NO + j] = fn2;
        sp[fi2] = -1.f;
      } else {
        out[r * NO + j] = -1.f;
        seln[r * NO + j] = -1;
      }
    }
    __syncthreads();
  }
}

// ---------- K6: exp_scores ----------

__global__ void k_expand(const float* __restrict__ scores,
                         const double* __restrict__ sums,
                         const float* __restrict__ rowstats,
                         const float* __restrict__ colmax,
                         const float* __restrict__ collse,
                         const int* __restrict__ seln,
                         float* __restrict__ out,
                         int N, int NO) {
  int b = blockIdx.x;
  int r2 = threadIdx.x;
  int n = seln[b];
  float v = 0.f;
  if (n >= 0) {
    float fmu, istd;
    get_mu_istd(sums, N, fmu, istd);
    float x = scores[(size_t)r2 * N + n];
    float v1 = (x - rowstats[r2]) * istd - rowstats[64 + r2];
    float v2 = (x - colmax[n]) * istd - collse[n];
    v = v1 + v2;
  }
  out[RR * NO + (size_t)b * RR + r2] = v;
}

// ---------- launch ----------

extern "C" void kernel_launch(void* const* d_in, const int* in_sizes, int n_in,
                              void* d_out, int out_size, void* d_ws, size_t ws_size,
                              hipStream_t stream) {
  const float* hs = (const float*)d_in[0];
  const float* es = (const float*)d_in[1];
  const float* W = (const float*)d_in[2];
  const void* mask = d_in[3];

  const int N = in_sizes[1] / DD;               // 200000
  const int NO = out_size / (RR * (1 + RR));    // 50
  const int NB = (N + 255) / 256;

  char* ws = (char*)d_ws;
  size_t o = 0;
  float* scores = (float*)(ws + o);   o += (size_t)RR * N * 4;
  float* hsW = (float*)(ws + o);      o += RR * DD * 4;
  o = (o + 255) & ~(size_t)255;
  // zero region: sums(16) + cnt(256)
  double* sums = (double*)(ws + o);
  int* cnt = (int*)(ws + o + 16);
  size_t zero_off = o, zero_bytes = 16 + 256;
  o += 512;
  float* rowstats = (float*)(ws + o); o += 256 * 4;
  float* rowmaxf = (float*)(ws + o);  o += 128 * 4;
  o = (o + 255) & ~(size_t)255;
  float* colmax = (float*)(ws + o);   o += (size_t)N * 4;
  int* colargmax = (int*)(ws + o);    o += (size_t)N * 4;
  float* collse = (float*)(ws + o);   o += (size_t)N * 4;
  o = (o + 255) & ~(size_t)255;
  unsigned long long* mbits = (unsigned long long*)(ws + o); o += (size_t)N * 8;
  o = (o + 255) & ~(size_t)255;
  float* candx = (float*)(ws + o);    o += (size_t)RR * CAP * 4;
  int* candn = (int*)(ws + o);        o += (size_t)RR * CAP * 4;
  int* seln = (int*)(ws + o);         o += (size_t)RR * NO * 4;
  o = (o + 255) & ~(size_t)255;
  float* qpart = (float*)(ws + o);    o += (size_t)NB * 128 * 4;
  double* spart = (double*)(ws + o);  o += (size_t)NB * 2 * 8;
  float* colpart = (float*)(ws + o);  o += (size_t)NB * 128 * 4;

  hipMemsetAsync(ws + zero_off, 0, zero_bytes, stream);

  k_mask<<<NB, 256, 0, stream>>>(mask, mbits, N);
  k_hsw<<<RR, 256, 0, stream>>>(hs, W, hsW);
  k_scores<<<NB, 256, 0, stream>>>(es, hsW, mbits, scores, colmax, colargmax,
                                   qpart, spart, N);
  k_redmax<<<128, 256, 0, stream>>>(qpart, rowmaxf, NB);
  k_redsum<<<1, 256, 0, stream>>>(spart, sums, NB);
  k_colpass<<<NB, 256, 0, stream>>>(scores, colmax, colargmax, mbits, sums, rowmaxf,
                                    collse, colpart, cnt, candx, candn, N);
  k_redacc<<<128, 256, 0, stream>>>(colpart, rowmaxf, rowstats, NB);
  k_topk<<<RR, 512, 0, stream>>>(cnt, candx, candn, sums, rowstats, (float*)d_out, seln,
                                 N, NO);
  k_expand<<<RR * NO, 64, 0, stream>>>(scores, sums, rowstats, colmax, collse, seln,
                                       (float*)d_out, N, NO);
}

// Round 6
// 590.600 us; speedup vs baseline: 3.3378x; 1.0713x over previous
//
#include <hip/hip_runtime.h>
#include <math.h>

#define RR 64
#define DD 256
#define CAP 6144

// ---------- helpers ----------

__device__ __forceinline__ void get_mu_istd(const double* sums, int N, float& fmu, float& istd) {
  double M = (double)RR * (double)N;
  double mu = sums[0] / M;
  double var = (sums[1] - sums[0] * sums[0] / M) / (M - 1.0);
  fmu = (float)mu;
  istd = (float)(1.0 / sqrt(var));
}

// async global->LDS, 16B per lane. LDS dest = wave-uniform base + lane*16.
__device__ __forceinline__ void cp16(const void* g, void* l) {
  __builtin_amdgcn_global_load_lds((const __attribute__((address_space(1))) void*)g,
                                   (__attribute__((address_space(3))) void*)l, 16, 0, 0);
}

// ---------- K_mask: per-block dtype sniff + pack (round-11: vectorized) ----------
// Wave ty owns rows [16ty,16ty+16); thread owns 4 consecutive cols via
// uchar4/float4/int4 loads (16 vector loads vs 64 scalar strided). Partial
// 16-bit groups combined through LDS u16 [4][256].

__global__ __launch_bounds__(256) void k_mask(const void* __restrict__ maskp,
                                              unsigned long long* __restrict__ mbits,
                                              int N) {
  __shared__ int f;
  __shared__ unsigned short pb[4][256];
  int tid = threadIdx.x;
  if (tid == 0) f = 0;
  __syncthreads();
  {
    const unsigned* mw = (const unsigned*)maskp;
    int mode = 0;
    for (int i = tid; i < 4096; i += 256) {
      unsigned v = mw[i];
      if (v == 0x3f800000u) mode = 2;
      else if (v > 1u && mode != 2) mode = 1;
    }
    if (mode) atomicMax(&f, mode);
  }
  __syncthreads();
  const int mode = f;

  const int lane = tid & 63, ty = tid >> 6;
  const int R0 = ty * 16;
  const int n0 = blockIdx.x * 256;
  const int n4 = n0 + lane * 4;
  unsigned g0 = 0, g1 = 0, g2 = 0, g3 = 0;
  const bool vec_ok = (n4 + 3) < N;

  if (mode == 1) {
    const unsigned char* m = (const unsigned char*)maskp;
    if (vec_ok) {
#pragma unroll
      for (int i = 0; i < 16; ++i) {
        uchar4 v = *(const uchar4*)(m + (size_t)(R0 + i) * N + n4);
        g0 |= (unsigned)(v.x != 0) << i;
        g1 |= (unsigned)(v.y != 0) << i;
        g2 |= (unsigned)(v.z != 0) << i;
        g3 |= (unsigned)(v.w != 0) << i;
      }
    } else {
      unsigned* gp[4] = {&g0, &g1, &g2, &g3};
      for (int c = 0; c < 4; ++c)
        if (n4 + c < N)
          for (int i = 0; i < 16; ++i)
            *gp[c] |= (unsigned)(m[(size_t)(R0 + i) * N + n4 + c] != 0) << i;
    }
  } else if (mode == 2) {
    const float* m = (const float*)maskp;
    if (vec_ok) {
#pragma unroll
      for (int i = 0; i < 16; ++i) {
        float4 v = *(const float4*)(m + (size_t)(R0 + i) * N + n4);
        g0 |= (unsigned)(v.x != 0.f) << i;
        g1 |= (unsigned)(v.y != 0.f) << i;
        g2 |= (unsigned)(v.z != 0.f) << i;
        g3 |= (unsigned)(v.w != 0.f) << i;
      }
    } else {
      unsigned* gp[4] = {&g0, &g1, &g2, &g3};
      for (int c = 0; c < 4; ++c)
        if (n4 + c < N)
          for (int i = 0; i < 16; ++i)
            *gp[c] |= (unsigned)(m[(size_t)(R0 + i) * N + n4 + c] != 0.f) << i;
    }
  } else {
    const int* m = (const int*)maskp;
    if (vec_ok) {
#pragma unroll
      for (int i = 0; i < 16; ++i) {
        int4 v = *(const int4*)(m + (size_t)(R0 + i) * N + n4);
        g0 |= (unsigned)(v.x != 0) << i;
        g1 |= (unsigned)(v.y != 0) << i;
        g2 |= (unsigned)(v.z != 0) << i;
        g3 |= (unsigned)(v.w != 0) << i;
      }
    } else {
      unsigned* gp[4] = {&g0, &g1, &g2, &g3};
      for (int c = 0; c < 4; ++c)
        if (n4 + c < N)
          for (int i = 0; i < 16; ++i)
            *gp[c] |= (unsigned)(m[(size_t)(R0 + i) * N + n4 + c] != 0) << i;
    }
  }
  pb[ty][lane * 4 + 0] = (unsigned short)g0;
  pb[ty][lane * 4 + 1] = (unsigned short)g1;
  pb[ty][lane * 4 + 2] = (unsigned short)g2;
  pb[ty][lane * 4 + 3] = (unsigned short)g3;
  __syncthreads();
  const int n = n0 + tid;
  if (n < N) {
    mbits[n] = (unsigned long long)pb[0][tid] |
               ((unsigned long long)pb[1][tid] << 16) |
               ((unsigned long long)pb[2][tid] << 32) |
               ((unsigned long long)pb[3][tid] << 48);
  }
}

// ---------- K1: hsW = hs @ W   [64 x 256] ----------

__global__ __launch_bounds__(256) void k_hsw(const float* __restrict__ hs,
                                             const float* __restrict__ W,
                                             float* __restrict__ hsW) {
  int i = blockIdx.x;
  int j = threadIdx.x;
  float acc = 0.f;
  for (int k = 0; k < DD; ++k) acc = fmaf(hs[i * DD + k], W[k * DD + j], acc);
  hsW[i * DD + j] = acc;
}

// ---------- K2: scores GEMM (UNCHANGED from round-10 verified: 170us) ----------

__global__ __launch_bounds__(256) void k_scores(const float* __restrict__ es,
                                                const float* __restrict__ hsW,
                                                const unsigned long long* __restrict__ mbits,
                                                float* __restrict__ scores,
                                                float* __restrict__ colmax,
                                                int* __restrict__ colargmax,
                                                float* __restrict__ qpart,   // [NB][128]
                                                double* __restrict__ spart,  // [NB][2]
                                                int N) {
  // LDS dwords: [0,16384) es dbuf (8192 each: 256 cols x 32 dw, granule-XOR)
  //             [16384,20480) w dbuf (2048 each: (k>>4)*1024 + row*16 + (k&15))
  __shared__ float lds[20480];   // 80 KB exactly -> 2 blocks/CU
  const int tid = threadIdx.x;
  const int lane = tid & 63;
  const int ty = __builtin_amdgcn_readfirstlane(tid >> 6);
  const int n0 = blockIdx.x * 256;
  const int R0 = ty * 16;
  const int nb = n0 + lane;    // col c -> nb + 64*c

  const int srow = ty * 8 + (lane >> 3);
  const int sg4 = (((lane & 7) ^ ((lane >> 3) & 7)) << 2);
  const int wrow = ty * 16 + (lane >> 2);
  const int wg4 = (lane & 3) << 2;

  float4 acc[16];
#pragma unroll
  for (int i = 0; i < 16; ++i) acc[i] = make_float4(0.f, 0.f, 0.f, 0.f);

  auto stage = [&](float* ebase, float* wbase, int kc) {
#pragma unroll
    for (int p = 0; p < 8; ++p) {
      const int col = p * 32 + srow;
      const int rr = min(n0 + col, N - 1);
      cp16(es + (size_t)rr * DD + kc + sg4, ebase + p * 1024 + ty * 256);
    }
    cp16(hsW + (size_t)wrow * DD + kc + wg4, wbase + ty * 256);
    cp16(hsW + (size_t)wrow * DD + kc + 16 + wg4, wbase + 1024 + ty * 256);
  };

  stage(lds, lds + 16384, 0);
  asm volatile("s_waitcnt vmcnt(0)" ::: "memory");
  __syncthreads();

  const int swz = (lane & 7);

  for (int kc = 0; kc < DD; kc += 32) {
    const int cur = (kc >> 5) & 1;
    float* ebC = lds + (cur ? 8192 : 0);
    float* wbC = lds + 16384 + (cur ? 2048 : 0);
    if (kc + 32 < DD) {
      float* ebN = lds + (cur ? 0 : 8192);
      float* wbN = lds + 16384 + (cur ? 0 : 2048);
      stage(ebN, wbN, kc + 32);
    }
#pragma unroll
    for (int k = 0; k < 32; k += 4) {
      const int eswz = (((k >> 2) ^ swz) << 2);
      const float4 e0 = *(const float4*)(ebC + (lane       ) * 32 + eswz);
      const float4 e1 = *(const float4*)(ebC + (lane +  64 ) * 32 + eswz);
      const float4 e2 = *(const float4*)(ebC + (lane + 128 ) * 32 + eswz);
      const float4 e3 = *(const float4*)(ebC + (lane + 192 ) * 32 + eswz);
      const float* wk = wbC + ((k >> 4) * 1024) + (k & 15);
#pragma unroll
      for (int i = 0; i < 16; ++i) {
        const float4 w = *(const float4*)(wk + (R0 + i) * 16);
        acc[i].x = fmaf(w.x, e0.x, fmaf(w.y, e0.y, fmaf(w.z, e0.z, fmaf(w.w, e0.w, acc[i].x))));
        acc[i].y = fmaf(w.x, e1.x, fmaf(w.y, e1.y, fmaf(w.z, e1.z, fmaf(w.w, e1.w, acc[i].y))));
        acc[i].z = fmaf(w.x, e2.x, fmaf(w.y, e2.y, fmaf(w.z, e2.z, fmaf(w.w, e2.w, acc[i].z))));
        acc[i].w = fmaf(w.x, e3.x, fmaf(w.y, e3.y, fmaf(w.z, e3.z, fmaf(w.w, e3.w, acc[i].w))));
      }
    }
    asm volatile("s_waitcnt vmcnt(0)" ::: "memory");
    __syncthreads();
  }

  bool val[4];
#pragma unroll
  for (int c = 0; c < 4; ++c) val[c] = (nb + 64 * c) < N;

#pragma unroll
  for (int i = 0; i < 16; ++i) {
    float* dst = scores + (size_t)(R0 + i) * N + nb;
    float v[4] = {acc[i].x, acc[i].y, acc[i].z, acc[i].w};
#pragma unroll
    for (int c = 0; c < 4; ++c)
      if (val[c]) dst[64 * c] = v[c];
  }

  unsigned long long mb[4];
#pragma unroll
  for (int c = 0; c < 4; ++c) mb[c] = val[c] ? mbits[nb + 64 * c] : 0ull;

  float ps1[4], ps2[4], pcm[4], pbv[4];
  int pbr[4];
#pragma unroll
  for (int c = 0; c < 4; ++c) { ps1[c] = 0.f; ps2[c] = 0.f; pcm[c] = -INFINITY; pbv[c] = -INFINITY; pbr[c] = -1; }

#pragma unroll
  for (int i = 0; i < 16; ++i) {
    const int rrow = R0 + i;
    float v[4] = {acc[i].x, acc[i].y, acc[i].z, acc[i].w};
    float q = -INFINITY, qm = -INFINITY;
#pragma unroll
    for (int c = 0; c < 4; ++c) {
      ps1[c] += v[c];
      ps2[c] = fmaf(v[c], v[c], ps2[c]);
      pcm[c] = fmaxf(pcm[c], v[c]);
      bool bit = (mb[c] >> rrow) & 1ull;
      if (bit && (v[c] > pbv[c])) { pbv[c] = v[c]; pbr[c] = rrow; }
      float qv = val[c] ? v[c] : -INFINITY;
      q = fmaxf(q, qv);
      if (bit) qm = fmaxf(qm, qv);
    }
#pragma unroll
    for (int o = 32; o > 0; o >>= 1) {
      q = fmaxf(q, __shfl_down(q, o));
      qm = fmaxf(qm, __shfl_down(qm, o));
    }
    if (lane == 0) {
      qpart[(size_t)blockIdx.x * 128 + rrow] = q;
      qpart[(size_t)blockIdx.x * 128 + 64 + rrow] = qm;
    }
  }

  __syncthreads();
  float* Ls1 = lds;
  float* Ls2 = lds + 1024;
  float* Lcm = lds + 2048;
  float* Lbv = lds + 3072;
  int* Lbr = (int*)(lds + 4096);
  double* red = (double*)(lds + 5120);
#pragma unroll
  for (int c = 0; c < 4; ++c) {
    int col = lane + 64 * c;
    Ls1[ty * 256 + col] = ps1[c];
    Ls2[ty * 256 + col] = ps2[c];
    Lcm[ty * 256 + col] = pcm[c];
    Lbv[ty * 256 + col] = pbv[c];
    Lbr[ty * 256 + col] = pbr[c];
  }
  __syncthreads();

  const int n = n0 + tid;
  float s1 = 0.f, s2 = 0.f;
  if (n < N) {
    s1 = Ls1[tid] + Ls1[256 + tid] + Ls1[512 + tid] + Ls1[768 + tid];
    s2 = Ls2[tid] + Ls2[256 + tid] + Ls2[512 + tid] + Ls2[768 + tid];
    float cm = fmaxf(fmaxf(Lcm[tid], Lcm[256 + tid]), fmaxf(Lcm[512 + tid], Lcm[768 + tid]));
    colmax[n] = cm;
    float bv = -INFINITY;
    int br = -1;
#pragma unroll
    for (int w2 = 0; w2 < 4; ++w2) {
      float b = Lbv[w2 * 256 + tid];
      if (b > bv) { bv = b; br = Lbr[w2 * 256 + tid]; }
    }
    colargmax[n] = br;
  }

  double d1 = (double)s1, d2 = (double)s2;
#pragma unroll
  for (int o = 32; o > 0; o >>= 1) {
    d1 += __shfl_down(d1, o);
    d2 += __shfl_down(d2, o);
  }
  if ((tid & 63) == 0) { red[ty * 2] = d1; red[ty * 2 + 1] = d2; }
  __syncthreads();
  if (tid == 0) {
    spart[(size_t)blockIdx.x * 2] = red[0] + red[2] + red[4] + red[6];
    spart[(size_t)blockIdx.x * 2 + 1] = red[1] + red[3] + red[5] + red[7];
  }
}

// ---------- K2b: fused reduce: blocks 0..127 = row maxes; block 128 = sums + cnt zero ----------

__global__ __launch_bounds__(256) void k_redfuse(const float* __restrict__ qpart,
                                                 const double* __restrict__ spart,
                                                 float* __restrict__ rowmaxf,
                                                 double* __restrict__ sums,
                                                 int* __restrict__ cnt,
                                                 int NBlk) {
  const int tid = threadIdx.x, lane = tid & 63, ty = tid >> 6;
  if (blockIdx.x < 128) {
    const int slot = blockIdx.x;
    __shared__ float w[4];
    float m = -INFINITY;
    for (int i = tid; i < NBlk; i += 256) m = fmaxf(m, qpart[(size_t)i * 128 + slot]);
#pragma unroll
    for (int o = 32; o > 0; o >>= 1) m = fmaxf(m, __shfl_down(m, o));
    if (lane == 0) w[ty] = m;
    __syncthreads();
    if (tid == 0) rowmaxf[slot] = fmaxf(fmaxf(w[0], w[1]), fmaxf(w[2], w[3]));
  } else {
    __shared__ double r[8];
    double s0 = 0.0, s1 = 0.0;
    for (int i = tid; i < NBlk; i += 256) {
      s0 += spart[(size_t)i * 2];
      s1 += spart[(size_t)i * 2 + 1];
    }
#pragma unroll
    for (int o = 32; o > 0; o >>= 1) {
      s0 += __shfl_down(s0, o);
      s1 += __shfl_down(s1, o);
    }
    if (lane == 0) { r[ty * 2] = s0; r[ty * 2 + 1] = s1; }
    if (tid < RR) cnt[tid] = 0;   // re-zero per launch (replaces hipMemsetAsync)
    __syncthreads();
    if (tid == 0) {
      sums[0] = r[0] + r[2] + r[4] + r[6];
      sums[1] = r[1] + r[3] + r[5] + r[7];
    }
  }
}

// ---------- K4: fused column pass (round-11 rewrite) ----------
// Wave ty owns rows [16ty,16ty+16); thread owns 4 consecutive cols (float4
// loads, G13). Per-r shuffle chain now covers ALL 256 block-cols at once:
// 768 -> 192 shfl/thread (4x). Row partials are complete per-row values
// (rowU/rowM); column sums combine via 4KB LDS transpose. Scatter logic and
// cross-block cnt protocol identical to the verified version. xbr re-gathered
// from scores (bitwise-identical to the stored value).

__global__ __launch_bounds__(256) void k_colpass(const float* __restrict__ scores,
                                                 const float* __restrict__ colmax,
                                                 const int* __restrict__ colargmax,
                                                 const unsigned long long* __restrict__ mbits,
                                                 const double* __restrict__ sums,
                                                 const float* __restrict__ rowmaxf,
                                                 float* __restrict__ collse,
                                                 float* __restrict__ colpart,  // [NB][128]
                                                 int* __restrict__ cnt,
                                                 float* __restrict__ candx,
                                                 int* __restrict__ candn,
                                                 int N) {
  __shared__ float rmS[64], suS[64], smS[64];
  __shared__ float rowU[64], rowM[64];
  __shared__ float cpart[4][256];
  __shared__ int lcnt[64], lbase[64];
  const int tid = threadIdx.x, lane = tid & 63, ty = tid >> 6;
  const int R0 = ty * 16;
  float fmu, istd;
  get_mu_istd(sums, N, fmu, istd);
  if (tid < 64) {
    rmS[tid] = rowmaxf[tid];
    lcnt[tid] = 0;
  }
  __syncthreads();
  float gm = rmS[0];
#pragma unroll
  for (int r = 1; r < RR; ++r) gm = fmaxf(gm, rmS[r]);
  if (tid < 64) {
    suS[tid] = expf((gm - rmS[tid]) * istd);
    smS[tid] = expf((gm - rowmaxf[64 + tid]) * istd);
  }

  const int n0 = blockIdx.x * 256;
  const int n4 = n0 + lane * 4;
  bool vc[4];
  unsigned mbr[4];
#pragma unroll
  for (int c = 0; c < 4; ++c) {
    vc[c] = (n4 + c) < N;
    unsigned long long mw = vc[c] ? mbits[n4 + c] : 0ull;
    mbr[c] = (unsigned)((mw >> R0) & 0xffffull);
  }

  float cs0 = 0.f, cs1 = 0.f, cs2 = 0.f, cs3 = 0.f;
#pragma unroll
  for (int i = 0; i < 16; ++i) {
    const int r = R0 + i;
    const float4 x = *(const float4*)(scores + (size_t)r * N + n4);
    float E0 = vc[0] ? expf((x.x - gm) * istd) : 0.f;
    float E1 = vc[1] ? expf((x.y - gm) * istd) : 0.f;
    float E2 = vc[2] ? expf((x.z - gm) * istd) : 0.f;
    float E3 = vc[3] ? expf((x.w - gm) * istd) : 0.f;
    cs0 += E0; cs1 += E1; cs2 += E2; cs3 += E3;
    float eu = (E0 + E1) + (E2 + E3);
    float em = (((mbr[0] >> i) & 1u) ? E0 : 0.f) + (((mbr[1] >> i) & 1u) ? E1 : 0.f) +
               (((mbr[2] >> i) & 1u) ? E2 : 0.f) + (((mbr[3] >> i) & 1u) ? E3 : 0.f);
#pragma unroll
    for (int o = 32; o > 0; o >>= 1) {
      eu += __shfl_down(eu, o);
      em += __shfl_down(em, o);
    }
    if (lane == 0) { rowU[r] = eu; rowM[r] = em; }
  }

  cpart[ty][lane * 4 + 0] = cs0;
  cpart[ty][lane * 4 + 1] = cs1;
  cpart[ty][lane * 4 + 2] = cs2;
  cpart[ty][lane * 4 + 3] = cs3;
  __syncthreads();

  const int n = n0 + tid;
  const bool valid = n < N;
  int br = -1;
  if (valid) {
    float colsum = ((cpart[0][tid] + cpart[1][tid]) + cpart[2][tid]) + cpart[3][tid];
    collse[n] = logf(colsum) + (gm - colmax[n]) * istd;
    br = colargmax[n];
  }
  int lpos = 0;
  if (br >= 0) lpos = atomicAdd(&lcnt[br], 1);
  __syncthreads();
  if (tid < 64) {
    colpart[(size_t)blockIdx.x * 128 + tid] = rowU[tid] * suS[tid];
    colpart[(size_t)blockIdx.x * 128 + 64 + tid] = rowM[tid] * smS[tid];
    int c = lcnt[tid];
    lbase[tid] = c ? atomicAdd(&cnt[tid], c) : 0;
  }
  __syncthreads();
  if (br >= 0) {
    int pos = lbase[br] + lpos;
    if (pos < CAP) {
      candx[(size_t)br * CAP + pos] = scores[(size_t)br * N + n];
      candn[(size_t)br * CAP + pos] = n;
    }
  }
}

// ---------- K4b: reduce row exp-sum partials + finalize row stats ----------

__global__ __launch_bounds__(256) void k_redacc(const float* __restrict__ colpart,
                                                const float* __restrict__ rowmaxf,
                                                float* __restrict__ rowstats,
                                                int NBlk) {
  const int slot = blockIdx.x;   // 0..127
  const int tid = threadIdx.x, lane = tid & 63, ty = tid >> 6;
  __shared__ float w[4];
  float s = 0.f;
  for (int i = tid; i < NBlk; i += 256) s += colpart[(size_t)i * 128 + slot];
#pragma unroll
  for (int o = 32; o > 0; o >>= 1) s += __shfl_down(s, o);
  if (lane == 0) w[ty] = s;
  __syncthreads();
  if (tid == 0) {
    float total = w[0] + w[1] + w[2] + w[3];
    if (slot < 64) {
      rowstats[slot] = rowmaxf[slot];
      rowstats[64 + slot] = logf(total);
    } else {
      rowstats[128 + (slot - 64)] = rowmaxf[slot];
      rowstats[192 + (slot - 64)] = total;
    }
  }
}

// ---------- K5: per-row top-50 + fused expansion (k_expand absorbed) ----------

__global__ __launch_bounds__(512) void k_topkx(const int* __restrict__ cnt,
                                               const float* __restrict__ candx,
                                               const int* __restrict__ candn,
                                               const double* __restrict__ sums,
                                               const float* __restrict__ rowstats,
                                               const float* __restrict__ scores,
                                               const float* __restrict__ colmax,
                                               const float* __restrict__ collse,
                                               float* __restrict__ out,
                                               int N, int NO) {
  int r = blockIdx.x, tid = threadIdx.x;
  __shared__ float sp[CAP];
  __shared__ int sn[CAP];
  __shared__ float wp[8];
  __shared__ int wn[8], wi[8];
  __shared__ int selS[64];
  int c = min(cnt[r], CAP);
  float fmu, istd;
  get_mu_istd(sums, N, fmu, istd);
  const float rmm = rowstats[128 + r];
  const float lm = rowstats[192 + r];
  for (int i = tid; i < c; i += 512) {
    float xv = candx[(size_t)r * CAP + i];
    sp[i] = fmaxf(expf((xv - rmm) * istd) / lm, 1e-6f);
    sn[i] = candn[(size_t)r * CAP + i];
  }
  __syncthreads();
  for (int j = 0; j < NO; ++j) {
    float bp = -1.f;
    int bn = 0x7fffffff, bi = -1;
    for (int i = tid; i < c; i += 512) {
      float p = sp[i];
      int nn = sn[i];
      if (p > bp || (p == bp && nn < bn)) { bp = p; bn = nn; bi = i; }
    }
#pragma unroll
    for (int o = 32; o > 0; o >>= 1) {
      float p2 = __shfl_down(bp, o);
      int n2 = __shfl_down(bn, o);
      int i2 = __shfl_down(bi, o);
      if (p2 > bp || (p2 == bp && n2 < bn)) { bp = p2; bn = n2; bi = i2; }
    }
    if ((tid & 63) == 0) { wp[tid >> 6] = bp; wn[tid >> 6] = bn; wi[tid >> 6] = bi; }
    __syncthreads();
    if (tid == 0) {
      float fp2 = wp[0]; int fn2 = wn[0], fi2 = wi[0];
#pragma unroll
      for (int w2 = 1; w2 < 8; ++w2) {
        if (wp[w2] > fp2 || (wp[w2] == fp2 && wn[w2] < fn2)) { fp2 = wp[w2]; fn2 = wn[w2]; fi2 = wi[w2]; }
      }
      if (fp2 > 0.f) {
        out[r * NO + j] = (float)fn2;
        selS[j] = fn2;
        sp[fi2] = -1.f;
      } else {
        out[r * NO + j] = -1.f;
        selS[j] = -1;
      }
    }
    __syncthreads();
  }

  // ---- fused expansion: exp_scores for this row's 50 selections ----
  for (int idx = tid; idx < NO * RR; idx += 512) {
    const int j = idx >> 6;       // RR = 64
    const int r2 = idx & 63;
    const int n = selS[j];
    float v = 0.f;
    if (n >= 0) {
      float x = scores[(size_t)r2 * N + n];
      float v1 = (x - rowstats[r2]) * istd - rowstats[64 + r2];
      float v2 = (x - colmax[n]) * istd - collse[n];
      v = v1 + v2;
    }
    out[RR * NO + ((size_t)r * NO + j) * RR + r2] = v;
  }
}

// ---------- launch ----------

extern "C" void kernel_launch(void* const* d_in, const int* in_sizes, int n_in,
                              void* d_out, int out_size, void* d_ws, size_t ws_size,
                              hipStream_t stream) {
  const float* hs = (const float*)d_in[0];
  const float* es = (const float*)d_in[1];
  const float* W = (const float*)d_in[2];
  const void* mask = d_in[3];

  const int N = in_sizes[1] / DD;               // 200000
  const int NO = out_size / (RR * (1 + RR));    // 50
  const int NB = (N + 255) / 256;

  char* ws = (char*)d_ws;
  size_t o = 0;
  float* scores = (float*)(ws + o);   o += (size_t)RR * N * 4;
  float* hsW = (float*)(ws + o);      o += RR * DD * 4;
  o = (o + 255) & ~(size_t)255;
  double* sums = (double*)(ws + o);
  int* cnt = (int*)(ws + o + 16);
  o += 512;
  float* rowstats = (float*)(ws + o); o += 256 * 4;
  float* rowmaxf = (float*)(ws + o);  o += 128 * 4;
  o = (o + 255) & ~(size_t)255;
  float* colmax = (float*)(ws + o);   o += (size_t)N * 4;
  int* colargmax = (int*)(ws + o);    o += (size_t)N * 4;
  float* collse = (float*)(ws + o);   o += (size_t)N * 4;
  o = (o + 255) & ~(size_t)255;
  unsigned long long* mbits = (unsigned long long*)(ws + o); o += (size_t)N * 8;
  o = (o + 255) & ~(size_t)255;
  float* candx = (float*)(ws + o);    o += (size_t)RR * CAP * 4;
  int* candn = (int*)(ws + o);        o += (size_t)RR * CAP * 4;
  o = (o + 255) & ~(size_t)255;
  float* qpart = (float*)(ws + o);    o += (size_t)NB * 128 * 4;
  double* spart = (double*)(ws + o);  o += (size_t)NB * 2 * 8;
  float* colpart = (float*)(ws + o);  o += (size_t)NB * 128 * 4;

  k_mask<<<NB, 256, 0, stream>>>(mask, mbits, N);
  k_hsw<<<RR, 256, 0, stream>>>(hs, W, hsW);
  k_scores<<<NB, 256, 0, stream>>>(es, hsW, mbits, scores, colmax, colargmax,
                                   qpart, spart, N);
  k_redfuse<<<129, 256, 0, stream>>>(qpart, spart, rowmaxf, sums, cnt, NB);
  k_colpass<<<NB, 256, 0, stream>>>(scores, colmax, colargmax, mbits, sums, rowmaxf,
                                    collse, colpart, cnt, candx, candn, N);
  k_redacc<<<128, 256, 0, stream>>>(colpart, rowmaxf, rowstats, NB);
  k_topkx<<<RR, 512, 0, stream>>>(cnt, candx, candn, sums, rowstats, scores, colmax,
                                  collse, (float*)d_out, N, NO);
}

// Round 7
// 573.349 us; speedup vs baseline: 3.4383x; 1.0301x over previous
//
#include <hip/hip_runtime.h>
#include <math.h>

#define RR 64
#define DD 256
#define CAP 6144

// ---------- helpers ----------

__device__ __forceinline__ void get_mu_istd(const double* sums, int N, float& fmu, float& istd) {
  double M = (double)RR * (double)N;
  double mu = sums[0] / M;
  double var = (sums[1] - sums[0] * sums[0] / M) / (M - 1.0);
  fmu = (float)mu;
  istd = (float)(1.0 / sqrt(var));
}

// async global->LDS, 16B per lane. LDS dest = wave-uniform base + lane*16.
__device__ __forceinline__ void cp16(const void* g, void* l) {
  __builtin_amdgcn_global_load_lds((const __attribute__((address_space(1))) void*)g,
                                   (__attribute__((address_space(3))) void*)l, 16, 0, 0);
}

// ---------- K1: hsW = hs @ W   [64 x 256] ----------

__global__ __launch_bounds__(256) void k_hsw(const float* __restrict__ hs,
                                             const float* __restrict__ W,
                                             float* __restrict__ hsW) {
  int i = blockIdx.x;
  int j = threadIdx.x;
  float acc = 0.f;
  for (int k = 0; k < DD; ++k) acc = fmaf(hs[i * DD + k], W[k * DD + j], acc);
  hsW[i * DD + j] = acc;
}

// ---------- K2: scores GEMM ----------
// Round-12: 512-thread / 8-wave blocks, SAME 256-col tile, SAME LDS buffers,
// swizzles and global access pattern as the verified round-10 kernel.
// Rationale: at 2 blocks/CU x 4 waves = 2 streams/SIMD, neither VALU (49%)
// nor LDS was saturated -> latency-bound. 8-wave blocks double the streams
// per SIMD (4/SIMD) at the same LDS footprint. Wave owns 8 rows (acc 32
// VGPR); per-(row,col) FMA chain expression unchanged -> bitwise-same scores.
// Also absorbs k_mask: dtype sniff issues with the prologue staging (drained
// by the existing vmcnt(0)); pack via 2KB LDS byte transpose after the GEMM
// loop; writes mbits for k_colpass and feeds in-kernel stats directly.
// launch_bounds (512,4): VGPR cap 128 (need ~85) -> no forced spill (r2 lesson).

__global__ __launch_bounds__(512, 4) void k_scores(const float* __restrict__ es,
                                                   const float* __restrict__ hsW,
                                                   const void* __restrict__ maskp,
                                                   unsigned long long* __restrict__ mbits,
                                                   float* __restrict__ scores,
                                                   float* __restrict__ colmax,
                                                   int* __restrict__ colargmax,
                                                   float* __restrict__ qpart,   // [128][NB]
                                                   double* __restrict__ spart,  // [NB][2]
                                                   int N) {
  // LDS dwords: [0,16384) es dbuf (8192 each: 256 cols x 32 dw, granule-XOR)
  //             [16384,20480) w dbuf (2048 each: (k>>4)*1024 + row*16 + (k&15))
  // post-loop reuse: stat arrays [0,10272); pb bytes at dw 14336; f at 15000.
  __shared__ float lds[20480];   // 80 KB -> 2 blocks/CU (16 waves/CU)
  const int tid = threadIdx.x;
  const int lane = tid & 63;
  const int ty = __builtin_amdgcn_readfirstlane(tid >> 6);
  const int n0 = blockIdx.x * 256;
  const int NBg = gridDim.x;
  const int R0 = ty * 8;
  const int nb = n0 + lane;    // col c -> nb + 64*c

  int* fS = (int*)(lds + 15000);
  unsigned char* pb = (unsigned char*)(lds + 14336);  // [8][256] bytes

  if (tid == 0) *fS = 0;

  // staging coords (loop-invariant)
  const int sg4 = (((lane & 7) ^ ((lane >> 3) & 7)) << 2);  // pre-swizzled src granule
  const int wrow = (tid >> 2) & 63;
  const int whalf = tid >> 8;
  const int wg4 = (tid & 3) << 2;

  float4 acc[8];
#pragma unroll
  for (int i = 0; i < 8; ++i) acc[i] = make_float4(0.f, 0.f, 0.f, 0.f);

  auto stage = [&](float* ebase, float* wbase, int kc) {
#pragma unroll
    for (int p = 0; p < 4; ++p) {
      const int col = p * 64 + (tid >> 3);
      const int rr = min(n0 + col, N - 1);
      cp16(es + (size_t)rr * DD + kc + sg4, ebase + p * 2048 + ty * 256);
    }
    cp16(hsW + (size_t)wrow * DD + kc + whalf * 16 + wg4, wbase + ty * 256);
  };

  // prologue: stage chunk 0; mask dtype sniff rides the same vmcnt(0) drain
  stage(lds, lds + 16384, 0);
  int mymode = 0;
  {
    const unsigned* mw = (const unsigned*)maskp;
    for (int i = tid; i < 4096; i += 512) {
      unsigned v = mw[i];
      if (v == 0x3f800000u) mymode = 2;
      else if (v > 1u && mymode != 2) mymode = 1;
    }
  }
  asm volatile("s_waitcnt vmcnt(0)" ::: "memory");
  __syncthreads();
  if (mymode) atomicMax(fS, mymode);   // read after >=1 loop barrier -> visible

  const int swz = (lane & 7);

  for (int kc = 0; kc < DD; kc += 32) {
    const int cur = (kc >> 5) & 1;
    float* ebC = lds + (cur ? 8192 : 0);
    float* wbC = lds + 16384 + (cur ? 2048 : 0);
    if (kc + 32 < DD) {
      float* ebN = lds + (cur ? 0 : 8192);
      float* wbN = lds + 16384 + (cur ? 0 : 2048);
      stage(ebN, wbN, kc + 32);   // async; drains at loop-end barrier
    }
#pragma unroll
    for (int k = 0; k < 32; k += 4) {
      const int eswz = (((k >> 2) ^ swz) << 2);
      const float4 e0 = *(const float4*)(ebC + (lane       ) * 32 + eswz);
      const float4 e1 = *(const float4*)(ebC + (lane +  64 ) * 32 + eswz);
      const float4 e2 = *(const float4*)(ebC + (lane + 128 ) * 32 + eswz);
      const float4 e3 = *(const float4*)(ebC + (lane + 192 ) * 32 + eswz);
      const float* wk = wbC + ((k >> 4) * 1024) + (k & 15);
#pragma unroll
      for (int i = 0; i < 8; ++i) {
        const float4 w = *(const float4*)(wk + (R0 + i) * 16);  // uniform -> broadcast
        acc[i].x = fmaf(w.x, e0.x, fmaf(w.y, e0.y, fmaf(w.z, e0.z, fmaf(w.w, e0.w, acc[i].x))));
        acc[i].y = fmaf(w.x, e1.x, fmaf(w.y, e1.y, fmaf(w.z, e1.z, fmaf(w.w, e1.w, acc[i].y))));
        acc[i].z = fmaf(w.x, e2.x, fmaf(w.y, e2.y, fmaf(w.z, e2.z, fmaf(w.w, e2.w, acc[i].z))));
        acc[i].w = fmaf(w.x, e3.x, fmaf(w.y, e3.y, fmaf(w.z, e3.z, fmaf(w.w, e3.w, acc[i].w))));
      }
    }
    asm volatile("s_waitcnt vmcnt(0)" ::: "memory");
    __syncthreads();
  }

  // ---- col validity ----
  bool val[4];
#pragma unroll
  for (int c = 0; c < 4; ++c) val[c] = (nb + 64 * c) < N;

  // ---- store scores ----
#pragma unroll
  for (int i = 0; i < 8; ++i) {
    float* dst = scores + (size_t)(R0 + i) * N + nb;
    float v[4] = {acc[i].x, acc[i].y, acc[i].z, acc[i].w};
#pragma unroll
    for (int c = 0; c < 4; ++c)
      if (val[c]) dst[64 * c] = v[c];
  }

  // ---- mask pack (absorbed k_mask): wave ty packs rows R0..R0+8 ----
  const int mode = *fS;
  {
    const int n4 = n0 + lane * 4;
    unsigned g0 = 0, g1 = 0, g2 = 0, g3 = 0;
    const bool vec_ok = (n4 + 3) < N;
    if (mode == 1) {
      const unsigned char* m = (const unsigned char*)maskp;
      if (vec_ok) {
#pragma unroll
        for (int i = 0; i < 8; ++i) {
          uchar4 v = *(const uchar4*)(m + (size_t)(R0 + i) * N + n4);
          g0 |= (unsigned)(v.x != 0) << i;
          g1 |= (unsigned)(v.y != 0) << i;
          g2 |= (unsigned)(v.z != 0) << i;
          g3 |= (unsigned)(v.w != 0) << i;
        }
      } else {
        unsigned* gp[4] = {&g0, &g1, &g2, &g3};
        for (int c = 0; c < 4; ++c)
          if (n4 + c < N)
            for (int i = 0; i < 8; ++i)
              *gp[c] |= (unsigned)(m[(size_t)(R0 + i) * N + n4 + c] != 0) << i;
      }
    } else if (mode == 2) {
      const float* m = (const float*)maskp;
      if (vec_ok) {
#pragma unroll
        for (int i = 0; i < 8; ++i) {
          float4 v = *(const float4*)(m + (size_t)(R0 + i) * N + n4);
          g0 |= (unsigned)(v.x != 0.f) << i;
          g1 |= (unsigned)(v.y != 0.f) << i;
          g2 |= (unsigned)(v.z != 0.f) << i;
          g3 |= (unsigned)(v.w != 0.f) << i;
        }
      } else {
        unsigned* gp[4] = {&g0, &g1, &g2, &g3};
        for (int c = 0; c < 4; ++c)
          if (n4 + c < N)
            for (int i = 0; i < 8; ++i)
              *gp[c] |= (unsigned)(m[(size_t)(R0 + i) * N + n4 + c] != 0.f) << i;
      }
    } else {
      const int* m = (const int*)maskp;
      if (vec_ok) {
#pragma unroll
        for (int i = 0; i < 8; ++i) {
          int4 v = *(const int4*)(m + (size_t)(R0 + i) * N + n4);
          g0 |= (unsigned)(v.x != 0) << i;
          g1 |= (unsigned)(v.y != 0) << i;
          g2 |= (unsigned)(v.z != 0) << i;
          g3 |= (unsigned)(v.w != 0) << i;
        }
      } else {
        unsigned* gp[4] = {&g0, &g1, &g2, &g3};
        for (int c = 0; c < 4; ++c)
          if (n4 + c < N)
            for (int i = 0; i < 8; ++i)
              *gp[c] |= (unsigned)(m[(size_t)(R0 + i) * N + n4 + c] != 0) << i;
      }
    }
    pb[ty * 256 + lane * 4 + 0] = (unsigned char)g0;
    pb[ty * 256 + lane * 4 + 1] = (unsigned char)g1;
    pb[ty * 256 + lane * 4 + 2] = (unsigned char)g2;
    pb[ty * 256 + lane * 4 + 3] = (unsigned char)g3;
  }
  __syncthreads();

  // mbits assembly (for k_colpass)
  if (tid < 256) {
    const int n = n0 + tid;
    if (n < N) {
      unsigned long long b = 0;
#pragma unroll
      for (int w2 = 0; w2 < 8; ++w2)
        b |= (unsigned long long)pb[w2 * 256 + tid] << (8 * w2);
      mbits[n] = b;
    }
  }

  // mask bits for my 4 stat cols (own wave's 8 rows)
  unsigned mbr[4];
#pragma unroll
  for (int c = 0; c < 4; ++c) mbr[c] = pb[ty * 256 + lane + 64 * c];

  // ---- per-col partials over my 8 rows + fused row-max reductions ----
  float ps1[4], ps2[4], pcm[4], pbv[4];
  int pbr[4];
#pragma unroll
  for (int c = 0; c < 4; ++c) { ps1[c] = 0.f; ps2[c] = 0.f; pcm[c] = -INFINITY; pbv[c] = -INFINITY; pbr[c] = -1; }

#pragma unroll
  for (int i = 0; i < 8; ++i) {
    const int rrow = R0 + i;
    float v[4] = {acc[i].x, acc[i].y, acc[i].z, acc[i].w};
    float q = -INFINITY, qm = -INFINITY;
#pragma unroll
    for (int c = 0; c < 4; ++c) {
      ps1[c] += v[c];
      ps2[c] = fmaf(v[c], v[c], ps2[c]);
      pcm[c] = fmaxf(pcm[c], v[c]);
      bool bit = (mbr[c] >> i) & 1u;
      if (bit && (v[c] > pbv[c])) { pbv[c] = v[c]; pbr[c] = rrow; }
      float qv = val[c] ? v[c] : -INFINITY;
      q = fmaxf(q, qv);
      if (bit) qm = fmaxf(qm, qv);
    }
#pragma unroll
    for (int o = 32; o > 0; o >>= 1) {
      q = fmaxf(q, __shfl_down(q, o));
      qm = fmaxf(qm, __shfl_down(qm, o));
    }
    if (lane == 0) {
      qpart[(size_t)rrow * NBg + blockIdx.x] = q;          // transposed [slot][NB]
      qpart[(size_t)(64 + rrow) * NBg + blockIdx.x] = qm;
    }
  }

  // ---- cross-wave col-stat combine via LDS (8 partials per col) ----
  __syncthreads();
  float* Ls1 = lds;               // [8][256]
  float* Ls2 = lds + 2048;
  float* Lcm = lds + 4096;
  float* Lbv = lds + 6144;
  int* Lbr = (int*)(lds + 8192);
  double* red = (double*)(lds + 10240);   // 16 doubles
#pragma unroll
  for (int c = 0; c < 4; ++c) {
    int col = lane + 64 * c;
    Ls1[ty * 256 + col] = ps1[c];
    Ls2[ty * 256 + col] = ps2[c];
    Lcm[ty * 256 + col] = pcm[c];
    Lbv[ty * 256 + col] = pbv[c];
    Lbr[ty * 256 + col] = pbr[c];
  }
  __syncthreads();

  float s1 = 0.f, s2 = 0.f;
  if (tid < 256) {
    const int n = n0 + tid;
    if (n < N) {
      float cm = -INFINITY, bv = -INFINITY;
      int br = -1;
#pragma unroll
      for (int w2 = 0; w2 < 8; ++w2) {
        s1 += Ls1[w2 * 256 + tid];
        s2 += Ls2[w2 * 256 + tid];
        cm = fmaxf(cm, Lcm[w2 * 256 + tid]);
        float b = Lbv[w2 * 256 + tid];
        if (b > bv) { bv = b; br = Lbr[w2 * 256 + tid]; }
      }
      colmax[n] = cm;
      colargmax[n] = br;
    }
  }

  double d1 = (double)s1, d2 = (double)s2;
#pragma unroll
  for (int o = 32; o > 0; o >>= 1) {
    d1 += __shfl_down(d1, o);
    d2 += __shfl_down(d2, o);
  }
  if (lane == 0) { red[ty * 2] = d1; red[ty * 2 + 1] = d2; }
  __syncthreads();
  if (tid == 0) {
    double t1 = 0.0, t2 = 0.0;
#pragma unroll
    for (int w2 = 0; w2 < 8; ++w2) { t1 += red[w2 * 2]; t2 += red[w2 * 2 + 1]; }
    spart[(size_t)blockIdx.x * 2] = t1;
    spart[(size_t)blockIdx.x * 2 + 1] = t2;
  }
}

// ---------- K2b: fused reduce: blocks 0..127 = row maxes; block 128 = sums + cnt zero ----------
// qpart transposed [slot][NB] -> coalesced reads.

__global__ __launch_bounds__(256) void k_redfuse(const float* __restrict__ qpart,
                                                 const double* __restrict__ spart,
                                                 float* __restrict__ rowmaxf,
                                                 double* __restrict__ sums,
                                                 int* __restrict__ cnt,
                                                 int NBlk) {
  const int tid = threadIdx.x, lane = tid & 63, ty = tid >> 6;
  if (blockIdx.x < 128) {
    const int slot = blockIdx.x;
    __shared__ float w[4];
    float m = -INFINITY;
    for (int i = tid; i < NBlk; i += 256) m = fmaxf(m, qpart[(size_t)slot * NBlk + i]);
#pragma unroll
    for (int o = 32; o > 0; o >>= 1) m = fmaxf(m, __shfl_down(m, o));
    if (lane == 0) w[ty] = m;
    __syncthreads();
    if (tid == 0) rowmaxf[slot] = fmaxf(fmaxf(w[0], w[1]), fmaxf(w[2], w[3]));
  } else {
    __shared__ double r[8];
    double s0 = 0.0, s1 = 0.0;
    for (int i = tid; i < NBlk; i += 256) {
      s0 += spart[(size_t)i * 2];
      s1 += spart[(size_t)i * 2 + 1];
    }
#pragma unroll
    for (int o = 32; o > 0; o >>= 1) {
      s0 += __shfl_down(s0, o);
      s1 += __shfl_down(s1, o);
    }
    if (lane == 0) { r[ty * 2] = s0; r[ty * 2 + 1] = s1; }
    if (tid < RR) cnt[tid] = 0;
    __syncthreads();
    if (tid == 0) {
      sums[0] = r[0] + r[2] + r[4] + r[6];
      sums[1] = r[1] + r[3] + r[5] + r[7];
    }
  }
}

// ---------- K4: fused column pass (verified round-11 structure) ----------
// colpart transposed [slot][NB].

__global__ __launch_bounds__(256) void k_colpass(const float* __restrict__ scores,
                                                 const float* __restrict__ colmax,
                                                 const int* __restrict__ colargmax,
                                                 const unsigned long long* __restrict__ mbits,
                                                 const double* __restrict__ sums,
                                                 const float* __restrict__ rowmaxf,
                                                 float* __restrict__ collse,
                                                 float* __restrict__ colpart,  // [128][NB]
                                                 int* __restrict__ cnt,
                                                 float* __restrict__ candx,
                                                 int* __restrict__ candn,
                                                 int N) {
  __shared__ float rmS[64], suS[64], smS[64];
  __shared__ float rowU[64], rowM[64];
  __shared__ float cpart[4][256];
  __shared__ int lcnt[64], lbase[64];
  const int tid = threadIdx.x, lane = tid & 63, ty = tid >> 6;
  const int R0 = ty * 16;
  const int NBg = gridDim.x;
  float fmu, istd;
  get_mu_istd(sums, N, fmu, istd);
  if (tid < 64) {
    rmS[tid] = rowmaxf[tid];
    lcnt[tid] = 0;
  }
  __syncthreads();
  float gm = rmS[0];
#pragma unroll
  for (int r = 1; r < RR; ++r) gm = fmaxf(gm, rmS[r]);
  if (tid < 64) {
    suS[tid] = expf((gm - rmS[tid]) * istd);
    smS[tid] = expf((gm - rowmaxf[64 + tid]) * istd);
  }

  const int n0 = blockIdx.x * 256;
  const int n4 = n0 + lane * 4;
  bool vc[4];
  unsigned mbr[4];
#pragma unroll
  for (int c = 0; c < 4; ++c) {
    vc[c] = (n4 + c) < N;
    unsigned long long mw = vc[c] ? mbits[n4 + c] : 0ull;
    mbr[c] = (unsigned)((mw >> R0) & 0xffffull);
  }

  float cs0 = 0.f, cs1 = 0.f, cs2 = 0.f, cs3 = 0.f;
#pragma unroll
  for (int i = 0; i < 16; ++i) {
    const int r = R0 + i;
    const float4 x = *(const float4*)(scores + (size_t)r * N + n4);
    float E0 = vc[0] ? expf((x.x - gm) * istd) : 0.f;
    float E1 = vc[1] ? expf((x.y - gm) * istd) : 0.f;
    float E2 = vc[2] ? expf((x.z - gm) * istd) : 0.f;
    float E3 = vc[3] ? expf((x.w - gm) * istd) : 0.f;
    cs0 += E0; cs1 += E1; cs2 += E2; cs3 += E3;
    float eu = (E0 + E1) + (E2 + E3);
    float em = (((mbr[0] >> i) & 1u) ? E0 : 0.f) + (((mbr[1] >> i) & 1u) ? E1 : 0.f) +
               (((mbr[2] >> i) & 1u) ? E2 : 0.f) + (((mbr[3] >> i) & 1u) ? E3 : 0.f);
#pragma unroll
    for (int o = 32; o > 0; o >>= 1) {
      eu += __shfl_down(eu, o);
      em += __shfl_down(em, o);
    }
    if (lane == 0) { rowU[r] = eu; rowM[r] = em; }
  }

  cpart[ty][lane * 4 + 0] = cs0;
  cpart[ty][lane * 4 + 1] = cs1;
  cpart[ty][lane * 4 + 2] = cs2;
  cpart[ty][lane * 4 + 3] = cs3;
  __syncthreads();

  const int n = n0 + tid;
  const bool valid = n < N;
  int br = -1;
  if (valid) {
    float colsum = ((cpart[0][tid] + cpart[1][tid]) + cpart[2][tid]) + cpart[3][tid];
    collse[n] = logf(colsum) + (gm - colmax[n]) * istd;
    br = colargmax[n];
  }
  int lpos = 0;
  if (br >= 0) lpos = atomicAdd(&lcnt[br], 1);
  __syncthreads();
  if (tid < 64) {
    colpart[(size_t)tid * NBg + blockIdx.x] = rowU[tid] * suS[tid];
    colpart[(size_t)(64 + tid) * NBg + blockIdx.x] = rowM[tid] * smS[tid];
    int c = lcnt[tid];
    lbase[tid] = c ? atomicAdd(&cnt[tid], c) : 0;
  }
  __syncthreads();
  if (br >= 0) {
    int pos = lbase[br] + lpos;
    if (pos < CAP) {
      candx[(size_t)br * CAP + pos] = scores[(size_t)br * N + n];
      candn[(size_t)br * CAP + pos] = n;
    }
  }
}

// ---------- K4b: reduce row exp-sum partials + finalize row stats ----------

__global__ __launch_bounds__(256) void k_redacc(const float* __restrict__ colpart,
                                                const float* __restrict__ rowmaxf,
                                                float* __restrict__ rowstats,
                                                int NBlk) {
  const int slot = blockIdx.x;   // 0..127
  const int tid = threadIdx.x, lane = tid & 63, ty = tid >> 6;
  __shared__ float w[4];
  float s = 0.f;
  for (int i = tid; i < NBlk; i += 256) s += colpart[(size_t)slot * NBlk + i];
#pragma unroll
  for (int o = 32; o > 0; o >>= 1) s += __shfl_down(s, o);
  if (lane == 0) w[ty] = s;
  __syncthreads();
  if (tid == 0) {
    float total = w[0] + w[1] + w[2] + w[3];
    if (slot < 64) {
      rowstats[slot] = rowmaxf[slot];
      rowstats[64 + slot] = logf(total);
    } else {
      rowstats[128 + (slot - 64)] = rowmaxf[slot];
      rowstats[192 + (slot - 64)] = total;
    }
  }
}

// ---------- K5: per-row top-50 + fused expansion ----------

__global__ __launch_bounds__(512) void k_topkx(const int* __restrict__ cnt,
                                               const float* __restrict__ candx,
                                               const int* __restrict__ candn,
                                               const double* __restrict__ sums,
                                               const float* __restrict__ rowstats,
                                               const float* __restrict__ scores,
                                               const float* __restrict__ colmax,
                                               const float* __restrict__ collse,
                                               float* __restrict__ out,
                                               int N, int NO) {
  int r = blockIdx.x, tid = threadIdx.x;
  __shared__ float sp[CAP];
  __shared__ int sn[CAP];
  __shared__ float wp[8];
  __shared__ int wn[8], wi[8];
  __shared__ int selS[64];
  int c = min(cnt[r], CAP);
  float fmu, istd;
  get_mu_istd(sums, N, fmu, istd);
  const float rmm = rowstats[128 + r];
  const float lm = rowstats[192 + r];
  for (int i = tid; i < c; i += 512) {
    float xv = candx[(size_t)r * CAP + i];
    sp[i] = fmaxf(expf((xv - rmm) * istd) / lm, 1e-6f);
    sn[i] = candn[(size_t)r * CAP + i];
  }
  __syncthreads();
  for (int j = 0; j < NO; ++j) {
    float bp = -1.f;
    int bn = 0x7fffffff, bi = -1;
    for (int i = tid; i < c; i += 512) {
      float p = sp[i];
      int nn = sn[i];
      if (p > bp || (p == bp && nn < bn)) { bp = p; bn = nn; bi = i; }
    }
#pragma unroll
    for (int o = 32; o > 0; o >>= 1) {
      float p2 = __shfl_down(bp, o);
      int n2 = __shfl_down(bn, o);
      int i2 = __shfl_down(bi, o);
      if (p2 > bp || (p2 == bp && n2 < bn)) { bp = p2; bn = n2; bi = i2; }
    }
    if ((tid & 63) == 0) { wp[tid >> 6] = bp; wn[tid >> 6] = bn; wi[tid >> 6] = bi; }
    __syncthreads();
    if (tid == 0) {
      float fp2 = wp[0]; int fn2 = wn[0], fi2 = wi[0];
#pragma unroll
      for (int w2 = 1; w2 < 8; ++w2) {
        if (wp[w2] > fp2 || (wp[w2] == fp2 && wn[w2] < fn2)) { fp2 = wp[w2]; fn2 = wn[w2]; fi2 = wi[w2]; }
      }
      if (fp2 > 0.f) {
        out[r * NO + j] = (float)fn2;
        selS[j] = fn2;
        sp[fi2] = -1.f;
      } else {
        out[r * NO + j] = -1.f;
        selS[j] = -1;
      }
    }
    __syncthreads();
  }

  for (int idx = tid; idx < NO * RR; idx += 512) {
    const int j = idx >> 6;       // RR = 64
    const int r2 = idx & 63;
    const int n = selS[j];
    float v = 0.f;
    if (n >= 0) {
      float x = scores[(size_t)r2 * N + n];
      float v1 = (x - rowstats[r2]) * istd - rowstats[64 + r2];
      float v2 = (x - colmax[n]) * istd - collse[n];
      v = v1 + v2;
    }
    out[RR * NO + ((size_t)r * NO + j) * RR + r2] = v;
  }
}

// ---------- launch ----------

extern "C" void kernel_launch(void* const* d_in, const int* in_sizes, int n_in,
                              void* d_out, int out_size, void* d_ws, size_t ws_size,
                              hipStream_t stream) {
  const float* hs = (const float*)d_in[0];
  const float* es = (const float*)d_in[1];
  const float* W = (const float*)d_in[2];
  const void* mask = d_in[3];

  const int N = in_sizes[1] / DD;               // 200000
  const int NO = out_size / (RR * (1 + RR));    // 50
  const int NB = (N + 255) / 256;

  char* ws = (char*)d_ws;
  size_t o = 0;
  float* scores = (float*)(ws + o);   o += (size_t)RR * N * 4;
  float* hsW = (float*)(ws + o);      o += RR * DD * 4;
  o = (o + 255) & ~(size_t)255;
  double* sums = (double*)(ws + o);
  int* cnt = (int*)(ws + o + 16);
  o += 512;
  float* rowstats = (float*)(ws + o); o += 256 * 4;
  float* rowmaxf = (float*)(ws + o);  o += 128 * 4;
  o = (o + 255) & ~(size_t)255;
  float* colmax = (float*)(ws + o);   o += (size_t)N * 4;
  int* colargmax = (int*)(ws + o);    o += (size_t)N * 4;
  float* collse = (float*)(ws + o);   o += (size_t)N * 4;
  o = (o + 255) & ~(size_t)255;
  unsigned long long* mbits = (unsigned long long*)(ws + o); o += (size_t)N * 8;
  o = (o + 255) & ~(size_t)255;
  float* candx = (float*)(ws + o);    o += (size_t)RR * CAP * 4;
  int* candn = (int*)(ws + o);        o += (size_t)RR * CAP * 4;
  o = (o + 255) & ~(size_t)255;
  float* qpart = (float*)(ws + o);    o += (size_t)NB * 128 * 4;
  double* spart = (double*)(ws + o);  o += (size_t)NB * 2 * 8;
  float* colpart = (float*)(ws + o);  o += (size_t)NB * 128 * 4;

  k_hsw<<<RR, 256, 0, stream>>>(hs, W, hsW);
  k_scores<<<NB, 512, 0, stream>>>(es, hsW, mask, mbits, scores, colmax, colargmax,
                                   qpart, spart, N);
  k_redfuse<<<129, 256, 0, stream>>>(qpart, spart, rowmaxf, sums, cnt, NB);
  k_colpass<<<NB, 256, 0, stream>>>(scores, colmax, colargmax, mbits, sums, rowmaxf,
                                    collse, colpart, cnt, candx, candn, N);
  k_redacc<<<128, 256, 0, stream>>>(colpart, rowmaxf, rowstats, NB);
  k_topkx<<<RR, 512, 0, stream>>>(cnt, candx, candn, sums, rowstats, scores, colmax,
                                  collse, (float*)d_out, N, NO);
}